// Round 1
// baseline (1628.181 us; speedup 1.0000x reference)
//
#include <hip/hip_runtime.h>
#include <hip/hip_bf16.h>
#include <math.h>

#define BB 8
#define HH 512
#define WW 512
#define HWH (HH*WW)
#define NID 15
#define NSEG (BB*NID)

// ---------------- zero workspace ----------------
__global__ void zero_ws(unsigned int* p, size_t nwords){
    size_t i = (size_t)blockIdx.x*blockDim.x + threadIdx.x;
    size_t stride = (size_t)gridDim.x*blockDim.x;
    for (; i < nwords; i += stride) p[i] = 0u;
}

// ---------------- phase1: per-id stats, bg_seed, focal ----------------
__global__ void phase1(const float* __restrict__ pred, const int* __restrict__ labels,
                       const int* __restrict__ inst,
                       float* __restrict__ stats, float* __restrict__ bgseed,
                       float* __restrict__ focal){
    int b = blockIdx.x >> 10;            // 1024 blocks per image
    int base = (blockIdx.x & 1023) * 256;
    int t = threadIdx.x;
    int p = base + t;

    __shared__ float st[NID][4];
    __shared__ float bacc, facc;
    if (t < NID*4) ((float*)st)[t] = 0.0f;
    if (t == 60) bacc = 0.0f;
    if (t == 61) facc = 0.0f;
    __syncthreads();

    const float* pb = pred + (size_t)b*6*HWH;
    float sg = pb[2*HWH + p];
    float z3 = pb[3*HWH + p], z4 = pb[4*HWH + p], z5 = pb[5*HWH + p];
    int id = inst[(size_t)b*HWH + p];
    const int* lb = labels + (size_t)b*3*HWH;
    int l0 = lb[p], l1 = lb[HWH + p], l2 = lb[2*HWH + p];

    float seed = 1.0f/(1.0f + expf(-z5));
    const float SC = 2.0f/511.0f;
    int w = p & 511, h = p >> 9;

    if (id > 0){
        int k = id - 1;
        atomicAdd(&st[k][0], 1.0f);
        atomicAdd(&st[k][1], (float)w * SC);
        atomicAdd(&st[k][2], (float)h * SC);
        atomicAdd(&st[k][3], sg);
    }
    float bgv = (l2 == 0) ? seed*seed : 0.0f;

    // focal (classes map to channels 3,4,5)
    int tc = 0; int best = l0;
    if (l1 > best){ tc = 1; best = l1; }
    if (l2 > best){ tc = 2; }
    float m = fmaxf(z3, fmaxf(z4, z5));
    float e3 = expf(z3 - m), e4 = expf(z4 - m), e5 = expf(z5 - m);
    float lse = m + logf(e3 + e4 + e5);
    float zt = (tc == 0) ? z3 : ((tc == 1) ? z4 : z5);
    float lp = zt - lse;
    float pt = expf(lp);
    float f = -(1.0f - pt)*(1.0f - pt)*lp;

    // wave reduce f and bgv
    for (int o = 32; o; o >>= 1){
        f   += __shfl_xor(f, o);
        bgv += __shfl_xor(bgv, o);
    }
    if ((t & 63) == 0){
        atomicAdd(&facc, f);
        atomicAdd(&bacc, bgv);
    }
    __syncthreads();

    if (t < NID*4) atomicAdd(&stats[(size_t)b*NID*4 + t], ((float*)st)[t]);
    if (t == 60) atomicAdd(&bgseed[b], bacc);
    if (t == 61) atomicAdd(&focal[0], facc);
}

// ---------------- phase2: derive centers, s ----------------
__global__ void phase2(const float* __restrict__ stats, float* __restrict__ derived){
    int seg = blockIdx.x*blockDim.x + threadIdx.x;
    if (seg < NSEG){
        float cnt = stats[seg*4+0];
        float safe = fmaxf(cnt, 1.0f);
        float cx = stats[seg*4+1]/safe;
        float cy = stats[seg*4+2]/safe;
        float sm = stats[seg*4+3]/safe;
        derived[seg*4+0] = cx;
        derived[seg*4+1] = cy;
        derived[seg*4+2] = expf(10.0f*sm);
        derived[seg*4+3] = sm;
    }
}

// ---------------- phase3: dist + histogram + var/seed_fg ----------------
__global__ void phase3(const float* __restrict__ pred, const int* __restrict__ inst,
                       const float* __restrict__ derived,
                       unsigned long long* __restrict__ hist,
                       float* __restrict__ results, int NB){
    int b = blockIdx.x >> 10;
    int base = (blockIdx.x & 1023) * 256;
    int t = threadIdx.x;

    __shared__ float cx[NID], cy[NID], ssf[NID], smf[NID];
    __shared__ float vacc[NID], sacc[NID];
    if (t < NID){
        const float* d0 = derived + (size_t)(b*NID + t)*4;
        cx[t] = d0[0]; cy[t] = d0[1]; ssf[t] = d0[2]; smf[t] = d0[3];
        vacc[t] = 0.0f; sacc[t] = 0.0f;
    }
    __syncthreads();

    int p = base + t;
    const float* pb = pred + (size_t)b*6*HWH;
    float p0 = pb[p], p1 = pb[HWH + p], sg = pb[2*HWH + p], z5 = pb[5*HWH + p];
    int id = inst[(size_t)b*HWH + p];
    const float SC = 2.0f/511.0f;
    float ex = tanhf(p0) + (float)(p & 511)*SC;
    float ey = tanhf(p1) + (float)(p >> 9)*SC;
    float seed = 1.0f/(1.0f + expf(-z5));
    float halfNB = 0.5f*(float)NB;
    unsigned long long* hb = hist + (size_t)(b*NID)*NB;
    int lane = t & 63;

    for (int k = 0; k < NID; k++){
        float dx = ex - cx[k], dy = ey - cy[k];
        float r2 = dx*dx + dy*dy;
        float d = expf(-ssf[k]*r2);
        bool fg = (id == k + 1);
        float e = fg ? (2.0f - 2.0f*d) : (2.0f*d);
        int idx = (int)(e * halfNB);
        if (idx > NB - 1) idx = NB - 1;

        // hot-bucket (idx==0, bg) wave aggregation
        unsigned long long bal = __ballot(idx == 0 && !fg);
        if (idx == 0 && !fg){
            if (lane == __ffsll(bal) - 1)
                atomicAdd(&hb[(size_t)k*NB],
                          ((unsigned long long)__popcll(bal)) << 32);
        } else {
            atomicAdd(&hb[(size_t)k*NB + idx],
                      (1ULL << 32) | (unsigned long long)(fg ? 1 : 0));
        }
        if (fg){
            float vd = sg - smf[k];
            float sd = seed - d;
            atomicAdd(&vacc[k], vd*vd);
            atomicAdd(&sacc[k], sd*sd);
        }
    }
    __syncthreads();
    if (t < NID){
        atomicAdd(&results[(size_t)(b*NID + t)*3 + 1], vacc[t]);
        atomicAdd(&results[(size_t)(b*NID + t)*3 + 2], sacc[t]);
    }
}

// ---------------- phase4: lovasz from histogram (descending scan) ----------------
__global__ void phase4(const unsigned long long* __restrict__ hist,
                       const float* __restrict__ stats,
                       float* __restrict__ results, int NB){
    int seg = blockIdx.x;
    const unsigned long long* h = hist + (size_t)seg*NB;
    float G = stats[seg*4+0];
    int t = threadIdx.x;
    int bpt = NB >> 8;   // bins per thread (256 threads)

    __shared__ unsigned int sc[256], sgc[256];
    unsigned int c = 0, g = 0;
    for (int i = 0; i < bpt; i++){
        unsigned long long v = h[NB - 1 - (t*bpt + i)];
        c += (unsigned int)(v >> 32);
        g += (unsigned int)(v & 0xffffffffu);
    }
    sc[t] = c; sgc[t] = g;
    __syncthreads();
    if (t == 0){
        unsigned int rc = 0, rg = 0;
        for (int i = 0; i < 256; i++){
            unsigned int tc_ = sc[i], tg_ = sgc[i];
            sc[i] = rc; sgc[i] = rg;
            rc += tc_; rg += tg_;
        }
    }
    __syncthreads();

    float contrib = 0.0f;
    if (G > 0.0f){
        unsigned int n = sc[t], gg = sgc[t];
        float jac_prev = 0.0f;
        if (n > 0){
            float fn = (float)n, fg_ = (float)gg;
            jac_prev = 1.0f - (G - fg_)/(G + (fn - fg_));
        }
        float scale = 2.0f/(float)NB;
        for (int i = 0; i < bpt; i++){
            int bin = NB - 1 - (t*bpt + i);
            unsigned long long v = h[bin];
            if (v){
                unsigned int cc = (unsigned int)(v >> 32);
                unsigned int cg = (unsigned int)(v & 0xffffffffu);
                n += cc; gg += cg;
                float fn = (float)n, fg_ = (float)gg;
                float jac = 1.0f - (G - fg_)/(G + (fn - fg_));
                float ev = ((float)bin + 0.5f)*scale;
                contrib += ev * (jac - jac_prev);
                jac_prev = jac;
            }
        }
    }
    for (int o = 32; o; o >>= 1) contrib += __shfl_xor(contrib, o);
    __shared__ float wsum[4];
    if ((t & 63) == 0) wsum[t >> 6] = contrib;
    __syncthreads();
    if (t == 0) results[(size_t)seg*3 + 0] = wsum[0] + wsum[1] + wsum[2] + wsum[3];
}

// ---------------- phase5: final combine ----------------
__global__ void phase5(const float* __restrict__ stats, const float* __restrict__ results,
                       const float* __restrict__ bgseed, const float* __restrict__ focal,
                       float* __restrict__ out){
    __shared__ float per_b[BB];
    int t = threadIdx.x;
    if (t < BB){
        float nvalid = 0.0f, lsum = 0.0f, vsum = 0.0f, ssum = 0.0f;
        for (int k = 0; k < NID; k++){
            int seg = t*NID + k;
            float cnt = stats[seg*4+0];
            if (cnt > 0.0f){
                nvalid += 1.0f;
                lsum += results[seg*3+0];
                float safe = fmaxf(cnt, 1.0f);
                vsum += results[seg*3+1]/safe;
                ssum += results[seg*3+2];
            }
        }
        float nobj = fmaxf(nvalid, 1.0f);
        float instl = lsum/nobj;
        float varl  = vsum/nobj;
        float seedl = (bgseed[t] + ssum)/(float)HWH;
        per_b[t] = 1.0f*instl + 10.0f*varl + 1.0f*seedl;
    }
    __syncthreads();
    if (t == 0){
        float s = 0.0f;
        for (int b = 0; b < BB; b++) s += per_b[b];
        out[0] = s/(float)BB + focal[0]/(float)(BB*HWH);
    }
}

extern "C" void kernel_launch(void* const* d_in, const int* in_sizes, int n_in,
                              void* d_out, int out_size, void* d_ws, size_t ws_size,
                              hipStream_t stream){
    const float* pred  = (const float*)d_in[0];
    const int*   labels= (const int*)d_in[1];
    const int*   inst  = (const int*)d_in[2];
    float* out = (float*)d_out;

    // pick histogram resolution that fits the workspace
    int NB = 2048;
    const int cands[4] = {16384, 8192, 4096, 2048};
    for (int i = 0; i < 4; i++){
        if ((size_t)NSEG*(size_t)cands[i]*8ull + 8192ull <= ws_size){ NB = cands[i]; break; }
    }

    unsigned long long* hist = (unsigned long long*)d_ws;
    float* stats   = (float*)((char*)d_ws + (size_t)NSEG*(size_t)NB*8ull);
    float* derived = stats + NSEG*4;
    float* results = derived + NSEG*4;
    float* bgseed  = results + NSEG*3;
    float* focal   = bgseed + BB;

    size_t total_bytes = (size_t)NSEG*(size_t)NB*8ull + 6400ull;
    size_t nwords = total_bytes/4;

    hipLaunchKernelGGL(zero_ws, dim3(2048), dim3(256), 0, stream,
                       (unsigned int*)d_ws, nwords);
    hipLaunchKernelGGL(phase1, dim3(BB*1024), dim3(256), 0, stream,
                       pred, labels, inst, stats, bgseed, focal);
    hipLaunchKernelGGL(phase2, dim3(1), dim3(128), 0, stream, stats, derived);
    hipLaunchKernelGGL(phase3, dim3(BB*1024), dim3(256), 0, stream,
                       pred, inst, derived, hist, results, NB);
    hipLaunchKernelGGL(phase4, dim3(NSEG), dim3(256), 0, stream,
                       hist, stats, results, NB);
    hipLaunchKernelGGL(phase5, dim3(1), dim3(64), 0, stream,
                       stats, results, bgseed, focal, out);
}

// Round 2
// 266.394 us; speedup vs baseline: 6.1119x; 6.1119x over previous
//
#include <hip/hip_runtime.h>
#include <hip/hip_bf16.h>
#include <math.h>

#define BB 8
#define HWH (512*512)
#define NID 15
#define NSEG (BB*NID)
#define NB 4096
#define HALFNB 2048.0f

__device__ __forceinline__ float ftanh(float x){
    // tanh(x) = 1 - 2/(exp(2x)+1); exact formula, v_exp+v_rcp (~1ulp)
    float t = __expf(2.0f*x);
    return 1.0f - 2.0f*__builtin_amdgcn_rcpf(t + 1.0f);
}
__device__ __forceinline__ float fsigmoid(float x){
    return __builtin_amdgcn_rcpf(1.0f + __expf(-x));
}

// ---------------- zero small accumulators ----------------
__global__ void zero_small(float* p, int n){
    for (int i = threadIdx.x; i < n; i += blockDim.x) p[i] = 0.0f;
}

// ---------------- phase1: per-id stats, bg_seed, focal ----------------
__global__ void phase1(const float* __restrict__ pred, const int* __restrict__ labels,
                       const int* __restrict__ inst,
                       float* __restrict__ stats, float* __restrict__ bgseed,
                       float* __restrict__ focal){
    int b = blockIdx.x >> 10;
    int base = (blockIdx.x & 1023) * 256;
    int t = threadIdx.x;
    int p = base + t;

    __shared__ float st[NID][4];
    __shared__ float bacc, facc;
    if (t < NID*4) ((float*)st)[t] = 0.0f;
    if (t == 60) bacc = 0.0f;
    if (t == 61) facc = 0.0f;
    __syncthreads();

    const float* pb = pred + (size_t)b*6*HWH;
    float sg = pb[2*HWH + p];
    float z3 = pb[3*HWH + p], z4 = pb[4*HWH + p], z5 = pb[5*HWH + p];
    int id = inst[(size_t)b*HWH + p];
    const int* lb = labels + (size_t)b*3*HWH;
    int l0 = lb[p], l1 = lb[HWH + p], l2 = lb[2*HWH + p];

    float seed = 1.0f/(1.0f + expf(-z5));
    const float SC = 2.0f/511.0f;
    int w = p & 511, h = p >> 9;

    if (id > 0){
        int k = id - 1;
        atomicAdd(&st[k][0], 1.0f);
        atomicAdd(&st[k][1], (float)w * SC);
        atomicAdd(&st[k][2], (float)h * SC);
        atomicAdd(&st[k][3], sg);
    }
    float bgv = (l2 == 0) ? seed*seed : 0.0f;

    int tc = 0; int best = l0;
    if (l1 > best){ tc = 1; best = l1; }
    if (l2 > best){ tc = 2; }
    float m = fmaxf(z3, fmaxf(z4, z5));
    float e3 = expf(z3 - m), e4 = expf(z4 - m), e5 = expf(z5 - m);
    float lse = m + logf(e3 + e4 + e5);
    float zt = (tc == 0) ? z3 : ((tc == 1) ? z4 : z5);
    float lp = zt - lse;
    float pt = expf(lp);
    float f = -(1.0f - pt)*(1.0f - pt)*lp;

    for (int o = 32; o; o >>= 1){
        f   += __shfl_xor(f, o);
        bgv += __shfl_xor(bgv, o);
    }
    if ((t & 63) == 0){
        atomicAdd(&facc, f);
        atomicAdd(&bacc, bgv);
    }
    __syncthreads();

    if (t < NID*4) atomicAdd(&stats[(size_t)b*NID*4 + t], ((float*)st)[t]);
    if (t == 60) atomicAdd(&bgseed[b], bacc);
    if (t == 61) atomicAdd(&focal[0], facc);
}

// ---------------- prep: precompute spatial embeddings ex,ey ----------------
__global__ __launch_bounds__(256) void prep_exy(const float* __restrict__ pred,
                                                float* __restrict__ exy){
    int b = blockIdx.x >> 8;
    int q = (blockIdx.x & 255)*256 + threadIdx.x;   // float4 index within image
    const float4* p0 = (const float4*)(pred + (size_t)b*6*HWH);
    const float4* p1 = p0 + HWH/4;
    float4 a = p0[q], c = p1[q];
    int p = q*4;
    const float SC = 2.0f/511.0f;
    float gx = (float)(p & 511)*SC;
    float gy = (float)(p >> 9)*SC;
    float4 ex, ey;
    ex.x = ftanh(a.x) + gx;
    ex.y = ftanh(a.y) + gx + SC;
    ex.z = ftanh(a.z) + gx + 2.0f*SC;
    ex.w = ftanh(a.w) + gx + 3.0f*SC;
    ey.x = ftanh(c.x) + gy;
    ey.y = ftanh(c.y) + gy;
    ey.z = ftanh(c.z) + gy;
    ey.w = ftanh(c.w) + gy;
    ((float4*)(exy + (size_t)b*2*HWH))[q] = ex;
    ((float4*)(exy + (size_t)b*2*HWH + HWH))[q] = ey;
}

// ---------------- phase2: derive centers, s ----------------
__global__ void phase2(const float* __restrict__ stats, float* __restrict__ derived){
    int seg = blockIdx.x*blockDim.x + threadIdx.x;
    if (seg < NSEG){
        float cnt = stats[seg*4+0];
        float safe = fmaxf(cnt, 1.0f);
        derived[seg*4+0] = stats[seg*4+1]/safe;
        derived[seg*4+1] = stats[seg*4+2]/safe;
        float sm = stats[seg*4+3]/safe;
        derived[seg*4+2] = expf(10.0f*sm);
        derived[seg*4+3] = sm;
    }
}

// ---------------- phaseL: per-segment LDS histogram + Lovasz scan ----------------
template<int PRE>
__global__ __launch_bounds__(512) void phaseL(const float* __restrict__ pred,
        const int* __restrict__ inst, const float* __restrict__ exy,
        const float* __restrict__ derived, const float* __restrict__ stats,
        float* __restrict__ results){
    int seg = blockIdx.x;
    int b = seg / NID, k = seg % NID;
    int t = threadIdx.x;
    __shared__ unsigned int hc[NB], hg[NB];
    __shared__ unsigned int sc[512], sgc[512];
    __shared__ float wsum[8];
    for (int i = t; i < NB; i += 512){ hc[i] = 0u; hg[i] = 0u; }
    float cx = derived[seg*4+0], cy = derived[seg*4+1], s = derived[seg*4+2];
    __syncthreads();

    const int kk = k + 1;
    const float SC = 2.0f/511.0f;
    const int4* ii = (const int4*)(inst + (size_t)b*HWH);

    auto body = [&](float ex, float ey, int id){
        float dx = ex - cx, dy = ey - cy;
        float d = __expf(-s*(dx*dx + dy*dy));
        bool fg = (id == kk);
        float e = fg ? (2.0f - 2.0f*d) : (2.0f*d);
        int bin = (int)(e * HALFNB);
        if (bin > NB-1) bin = NB-1;
        atomicAdd(&hc[bin], 1u);
        if (fg) atomicAdd(&hg[bin], 1u);
    };

    if (PRE){
        const float4* exb = (const float4*)(exy + (size_t)b*2*HWH);
        const float4* eyb = (const float4*)(exy + (size_t)b*2*HWH + HWH);
        for (int q = t; q < HWH/4; q += 512){
            float4 ex4 = exb[q]; float4 ey4 = eyb[q]; int4 id4 = ii[q];
            body(ex4.x, ey4.x, id4.x);
            body(ex4.y, ey4.y, id4.y);
            body(ex4.z, ey4.z, id4.z);
            body(ex4.w, ey4.w, id4.w);
        }
    } else {
        const float4* p0 = (const float4*)(pred + (size_t)b*6*HWH);
        const float4* p1 = p0 + HWH/4;
        for (int q = t; q < HWH/4; q += 512){
            float4 a = p0[q]; float4 c = p1[q]; int4 id4 = ii[q];
            int p = q*4;
            float gx = (float)(p & 511)*SC;
            float gy = (float)(p >> 9)*SC;
            body(ftanh(a.x)+gx,          ftanh(c.x)+gy, id4.x);
            body(ftanh(a.y)+gx+SC,       ftanh(c.y)+gy, id4.y);
            body(ftanh(a.z)+gx+2.0f*SC,  ftanh(c.z)+gy, id4.z);
            body(ftanh(a.w)+gx+3.0f*SC,  ftanh(c.w)+gy, id4.w);
        }
    }
    __syncthreads();

    // descending scan over bins
    const int BPT = NB/512;  // 8
    unsigned int c = 0, g = 0;
    int base = t*BPT;
    #pragma unroll
    for (int i = 0; i < BPT; i++){
        int bin = NB-1 - (base+i);
        c += hc[bin]; g += hg[bin];
    }
    sc[t] = c; sgc[t] = g;
    __syncthreads();
    if (t == 0){
        unsigned int rc = 0, rg = 0;
        for (int i = 0; i < 512; i++){
            unsigned int a = sc[i], bq = sgc[i];
            sc[i] = rc; sgc[i] = rg;
            rc += a; rg += bq;
        }
    }
    __syncthreads();

    float G = stats[seg*4+0];
    float contrib = 0.0f;
    if (G > 0.0f){
        unsigned int n = sc[t], gg = sgc[t];
        float jp = 0.0f;
        if (n > 0){
            jp = 1.0f - (G - (float)gg)/(G + (float)(n - gg));
        }
        const float scale = 2.0f/(float)NB;
        #pragma unroll
        for (int i = 0; i < BPT; i++){
            int bin = NB-1 - (base+i);
            unsigned int cc = hc[bin], cg = hg[bin];
            if (cc | cg){
                n += cc; gg += cg;
                float j2 = 1.0f - (G - (float)gg)/(G + (float)(n - gg));
                contrib += ((float)bin + 0.5f)*scale*(j2 - jp);
                jp = j2;
            }
        }
    }
    for (int o = 32; o; o >>= 1) contrib += __shfl_xor(contrib, o);
    if ((t & 63) == 0) wsum[t >> 6] = contrib;
    __syncthreads();
    if (t == 0){
        float sres = 0.0f;
        for (int i = 0; i < 8; i++) sres += wsum[i];
        results[(size_t)seg*3 + 0] = sres;
    }
}

// ---------------- phase3b: var + seed_fg (each pixel: its own id only) ----------------
__global__ __launch_bounds__(256) void phase3b(const float* __restrict__ pred,
        const int* __restrict__ inst, const float* __restrict__ derived,
        float* __restrict__ results){
    int b = blockIdx.x >> 8;
    int q = (blockIdx.x & 255)*256 + threadIdx.x;
    int t = threadIdx.x;
    __shared__ float scx[NID], scy[NID], ss[NID], ssm[NID];
    __shared__ float vacc[NID], sacc[NID];
    if (t < NID){
        const float* d0 = derived + (size_t)(b*NID + t)*4;
        scx[t] = d0[0]; scy[t] = d0[1]; ss[t] = d0[2]; ssm[t] = d0[3];
        vacc[t] = 0.0f; sacc[t] = 0.0f;
    }
    __syncthreads();

    const float4* p0 = (const float4*)(pred + (size_t)b*6*HWH);
    const float4* p1 = p0 + HWH/4;
    const float4* p2 = p0 + 2*(HWH/4);
    const float4* p5 = p0 + 5*(HWH/4);
    const int4* ii = (const int4*)(inst + (size_t)b*HWH);
    float4 a = p0[q], c = p1[q], sg4 = p2[q], z54 = p5[q];
    int4 id4 = ii[q];
    int p = q*4;
    const float SC = 2.0f/511.0f;
    float gx = (float)(p & 511)*SC;
    float gy = (float)(p >> 9)*SC;

    auto body = [&](float pj0, float pj1, float sgv, float z5v, int id, float xoff){
        if (id > 0){
            int k = id - 1;
            float ex = ftanh(pj0) + gx + xoff;
            float ey = ftanh(pj1) + gy;
            float dx = ex - scx[k], dy = ey - scy[k];
            float d = __expf(-ss[k]*(dx*dx + dy*dy));
            float seed = fsigmoid(z5v);
            float vd = sgv - ssm[k];
            float sd = seed - d;
            atomicAdd(&vacc[k], vd*vd);
            atomicAdd(&sacc[k], sd*sd);
        }
    };
    body(a.x, c.x, sg4.x, z54.x, id4.x, 0.0f);
    body(a.y, c.y, sg4.y, z54.y, id4.y, SC);
    body(a.z, c.z, sg4.z, z54.z, id4.z, 2.0f*SC);
    body(a.w, c.w, sg4.w, z54.w, id4.w, 3.0f*SC);
    __syncthreads();
    if (t < NID){
        atomicAdd(&results[(size_t)(b*NID + t)*3 + 1], vacc[t]);
        atomicAdd(&results[(size_t)(b*NID + t)*3 + 2], sacc[t]);
    }
}

// ---------------- phase5: final combine ----------------
__global__ void phase5(const float* __restrict__ stats, const float* __restrict__ results,
                       const float* __restrict__ bgseed, const float* __restrict__ focal,
                       float* __restrict__ out){
    __shared__ float per_b[BB];
    int t = threadIdx.x;
    if (t < BB){
        float nvalid = 0.0f, lsum = 0.0f, vsum = 0.0f, ssum = 0.0f;
        for (int k = 0; k < NID; k++){
            int seg = t*NID + k;
            float cnt = stats[seg*4+0];
            if (cnt > 0.0f){
                nvalid += 1.0f;
                lsum += results[seg*3+0];
                float safe = fmaxf(cnt, 1.0f);
                vsum += results[seg*3+1]/safe;
                ssum += results[seg*3+2];
            }
        }
        float nobj = fmaxf(nvalid, 1.0f);
        per_b[t] = lsum/nobj + 10.0f*(vsum/nobj) + (bgseed[t] + ssum)/(float)HWH;
    }
    __syncthreads();
    if (t == 0){
        float s = 0.0f;
        for (int b = 0; b < BB; b++) s += per_b[b];
        out[0] = s/(float)BB + focal[0]/(float)(BB*HWH);
    }
}

extern "C" void kernel_launch(void* const* d_in, const int* in_sizes, int n_in,
                              void* d_out, int out_size, void* d_ws, size_t ws_size,
                              hipStream_t stream){
    const float* pred  = (const float*)d_in[0];
    const int*   labels= (const int*)d_in[1];
    const int*   inst  = (const int*)d_in[2];
    float* out = (float*)d_out;

    float* stats   = (float*)d_ws;           // NSEG*4
    float* derived = stats + NSEG*4;         // NSEG*4
    float* results = derived + NSEG*4;       // NSEG*3
    float* bgseed  = results + NSEG*3;       // BB
    float* focal   = bgseed + BB;            // 1
    int nsmall = NSEG*4 + NSEG*4 + NSEG*3 + BB + 1;

    float* exy = (float*)((char*)d_ws + 8192);
    size_t need_pre = 8192ull + (size_t)BB*2*HWH*4ull;
    bool pre = (ws_size >= need_pre);

    hipLaunchKernelGGL(zero_small, dim3(1), dim3(512), 0, stream, stats, nsmall);
    hipLaunchKernelGGL(phase1, dim3(BB*1024), dim3(256), 0, stream,
                       pred, labels, inst, stats, bgseed, focal);
    if (pre)
        hipLaunchKernelGGL(prep_exy, dim3(BB*256), dim3(256), 0, stream, pred, exy);
    hipLaunchKernelGGL(phase2, dim3(1), dim3(128), 0, stream, stats, derived);
    if (pre)
        hipLaunchKernelGGL(phaseL<1>, dim3(NSEG), dim3(512), 0, stream,
                           pred, inst, exy, derived, stats, results);
    else
        hipLaunchKernelGGL(phaseL<0>, dim3(NSEG), dim3(512), 0, stream,
                           pred, inst, exy, derived, stats, results);
    hipLaunchKernelGGL(phase3b, dim3(BB*256), dim3(256), 0, stream,
                       pred, inst, derived, results);
    hipLaunchKernelGGL(phase5, dim3(1), dim3(64), 0, stream,
                       stats, results, bgseed, focal, out);
}

// Round 3
// 172.311 us; speedup vs baseline: 9.4491x; 1.5460x over previous
//
#include <hip/hip_runtime.h>
#include <hip/hip_bf16.h>
#include <math.h>

#define BB 8
#define HWH (512*512)
#define NID 15
#define NSEG (BB*NID)
#define NB 4096
#define HALFNB 2048.0f

__device__ __forceinline__ float ftanh(float x){
    float t = __expf(2.0f*x);
    return 1.0f - 2.0f*__builtin_amdgcn_rcpf(t + 1.0f);
}
__device__ __forceinline__ float fsigmoid(float x){
    return __builtin_amdgcn_rcpf(1.0f + __expf(-x));
}

// ---------------- zero small accumulators ----------------
__global__ void zero_small(float* p, int n){
    for (int i = threadIdx.x; i < n; i += blockDim.x) p[i] = 0.0f;
}

// ---- phase1f: per-id stats (register acc), bg_seed, focal, + exy precompute ----
template<int PRE>
__global__ __launch_bounds__(256) void phase1f(const float* __restrict__ pred,
        const int* __restrict__ labels, const int* __restrict__ inst,
        float* __restrict__ exy, float* __restrict__ stats,
        float* __restrict__ bgseed_p, float* __restrict__ focal_p){
    int b = blockIdx.x >> 5;           // 32 blocks per image
    int chunk = blockIdx.x & 31;
    int t = threadIdx.x;

    float cnt[NID], sx[NID], sy[NID], ssg[NID];
    #pragma unroll
    for (int k = 0; k < NID; k++){ cnt[k]=0.f; sx[k]=0.f; sy[k]=0.f; ssg[k]=0.f; }
    float facc = 0.0f, bacc = 0.0f;

    const int Q = HWH/4;
    const float4* P = (const float4*)(pred + (size_t)b*6*HWH);
    const int4*   L = (const int4*)(labels + (size_t)b*3*HWH);
    const int4*   I = (const int4*)(inst + (size_t)b*HWH);
    float4* EX = (float4*)(exy + (size_t)b*2*HWH);
    float4* EY = EX + Q;
    const float SC = 2.0f/511.0f;

    for (int it = 0; it < 8; ++it){
        int q = chunk*2048 + it*256 + t;
        float4 sg4 = P[2*Q+q];
        float4 z3 = P[3*Q+q], z4 = P[4*Q+q], z5 = P[5*Q+q];
        int4 id4 = I[q];
        int4 l0 = L[q], l1 = L[Q+q], l2 = L[2*Q+q];
        int p = q*4;
        float gx = (float)(p & 511)*SC;
        float gy = (float)(p >> 9)*SC;
        if (PRE){
            float4 a = P[q], c = P[Q+q];
            float4 ex4, ey4;
            ex4.x = ftanh(a.x)+gx;        ey4.x = ftanh(c.x)+gy;
            ex4.y = ftanh(a.y)+gx+SC;     ey4.y = ftanh(c.y)+gy;
            ex4.z = ftanh(a.z)+gx+2*SC;   ey4.z = ftanh(c.z)+gy;
            ex4.w = ftanh(a.w)+gx+3*SC;   ey4.w = ftanh(c.w)+gy;
            EX[q] = ex4; EY[q] = ey4;
        }
        auto px = [&](float sgv, float z3v, float z4v, float z5v, int id,
                      int L0, int L1, int L2, float gxv){
            float seed = fsigmoid(z5v);
            if (L2 == 0) bacc += seed*seed;
            int tc = 0, best = L0;
            if (L1 > best){ tc = 1; best = L1; }
            if (L2 > best){ tc = 2; }
            float m = fmaxf(z3v, fmaxf(z4v, z5v));
            float e3 = __expf(z3v-m), e4 = __expf(z4v-m), e5 = __expf(z5v-m);
            float lse = m + __logf(e3+e4+e5);
            float zt = (tc==0) ? z3v : ((tc==1) ? z4v : z5v);
            float lp = zt - lse;
            float pt = __expf(lp);
            facc += -(1.0f-pt)*(1.0f-pt)*lp;
            #pragma unroll
            for (int k = 0; k < NID; k++){
                float msk = (id == k+1) ? 1.0f : 0.0f;
                cnt[k] += msk;
                sx[k]  = fmaf(msk, gxv, sx[k]);
                sy[k]  = fmaf(msk, gy,  sy[k]);
                ssg[k] = fmaf(msk, sgv, ssg[k]);
            }
        };
        px(sg4.x, z3.x, z4.x, z5.x, id4.x, l0.x, l1.x, l2.x, gx);
        px(sg4.y, z3.y, z4.y, z5.y, id4.y, l0.y, l1.y, l2.y, gx+SC);
        px(sg4.z, z3.z, z4.z, z5.z, id4.z, l0.z, l1.z, l2.z, gx+2*SC);
        px(sg4.w, z3.w, z4.w, z5.w, id4.w, l0.w, l1.w, l2.w, gx+3*SC);
    }

    // wave butterfly reduce (all lanes end with totals)
    #pragma unroll
    for (int k = 0; k < NID; k++){
        for (int o = 32; o; o >>= 1){
            cnt[k] += __shfl_xor(cnt[k], o);
            sx[k]  += __shfl_xor(sx[k],  o);
            sy[k]  += __shfl_xor(sy[k],  o);
            ssg[k] += __shfl_xor(ssg[k], o);
        }
    }
    for (int o = 32; o; o >>= 1){
        facc += __shfl_xor(facc, o);
        bacc += __shfl_xor(bacc, o);
    }
    if ((t & 63) == 0){
        float* sb = stats + (size_t)b*NID*4;
        #pragma unroll
        for (int k = 0; k < NID; k++){
            atomicAdd(&sb[k*4+0], cnt[k]);
            atomicAdd(&sb[k*4+1], sx[k]);
            atomicAdd(&sb[k*4+2], sy[k]);
            atomicAdd(&sb[k*4+3], ssg[k]);
        }
    }
    __shared__ float wred[4][2];
    if ((t & 63) == 0){ wred[t>>6][0] = facc; wred[t>>6][1] = bacc; }
    __syncthreads();
    if (t == 0){
        focal_p[blockIdx.x]  = wred[0][0]+wred[1][0]+wred[2][0]+wred[3][0];
        bgseed_p[blockIdx.x] = wred[0][1]+wred[1][1]+wred[2][1]+wred[3][1];
    }
}

// ---------------- phase2: derive centers, s ----------------
__global__ void phase2(const float* __restrict__ stats, float* __restrict__ derived){
    int seg = blockIdx.x*blockDim.x + threadIdx.x;
    if (seg < NSEG){
        float cnt = stats[seg*4+0];
        float safe = fmaxf(cnt, 1.0f);
        derived[seg*4+0] = stats[seg*4+1]/safe;
        derived[seg*4+1] = stats[seg*4+2]/safe;
        float sm = stats[seg*4+3]/safe;
        derived[seg*4+2] = expf(10.0f*sm);
        derived[seg*4+3] = sm;
    }
}

// ---- phaseLH: split per-segment LDS histogram, slab writeback ----
template<int PRE>
__global__ __launch_bounds__(512) void phaseLH(const float* __restrict__ pred,
        const int* __restrict__ inst, const float* __restrict__ exy,
        const float* __restrict__ derived, unsigned long long* __restrict__ part,
        int S){
    int idx = blockIdx.x;
    int b = idx & 7;                 // XCD affinity: image b -> XCD b
    int j = idx >> 3;
    int k = j % NID;
    int sp = j / NID;
    int seg = b*NID + k;
    int t = threadIdx.x;

    __shared__ unsigned long long h8[NB];
    for (int i = t; i < NB; i += 512) h8[i] = 0ULL;
    float cx = derived[seg*4+0], cy = derived[seg*4+1], s = derived[seg*4+2];
    __syncthreads();

    const int Q = HWH/4;
    int qps = Q / S;
    int q0 = sp * qps;
    const int4* I = (const int4*)(inst + (size_t)b*HWH);
    const float4* EX = (const float4*)(exy + (size_t)b*2*HWH);
    const float4* EY = EX + Q;
    const float4* P0 = (const float4*)(pred + (size_t)b*6*HWH);
    const float4* P1 = P0 + Q;
    const float SC = 2.0f/511.0f;
    const int kk = k + 1;

    auto px = [&](float ex, float ey, int id){
        float dx = ex - cx, dy = ey - cy;
        float d = __expf(-s*(dx*dx + dy*dy));
        bool fg = (id == kk);
        float e = fg ? (2.0f - 2.0f*d) : (2.0f*d);
        int bin = (int)(e * HALFNB);
        if (bin > NB-1) bin = NB-1;
        atomicAdd(&h8[bin], (1ULL << 32) | (unsigned long long)(fg ? 1 : 0));
    };

    for (int q = q0 + t; q < q0 + qps; q += 512){
        int4 id4 = I[q];
        float4 ex4, ey4;
        if (PRE){ ex4 = EX[q]; ey4 = EY[q]; }
        else {
            float4 a = P0[q], c = P1[q];
            int p = q*4;
            float gx = (float)(p & 511)*SC;
            float gy = (float)(p >> 9)*SC;
            ex4.x = ftanh(a.x)+gx;      ey4.x = ftanh(c.x)+gy;
            ex4.y = ftanh(a.y)+gx+SC;   ey4.y = ftanh(c.y)+gy;
            ex4.z = ftanh(a.z)+gx+2*SC; ey4.z = ftanh(c.z)+gy;
            ex4.w = ftanh(a.w)+gx+3*SC; ey4.w = ftanh(c.w)+gy;
        }
        px(ex4.x, ey4.x, id4.x);
        px(ex4.y, ey4.y, id4.y);
        px(ex4.z, ey4.z, id4.z);
        px(ex4.w, ey4.w, id4.w);
    }
    __syncthreads();
    unsigned long long* dst = part + ((size_t)seg*S + sp)*NB;
    for (int i = t; i < NB; i += 512) dst[i] = h8[i];
}

// ---- phaseLS: merge slabs + descending Lovasz scan (wave-parallel) ----
__global__ __launch_bounds__(512) void phaseLS(const unsigned long long* __restrict__ part,
        const float* __restrict__ stats, float* __restrict__ results, int S){
    int idx = blockIdx.x;        // 120 = 8 images x 15 ids
    int b = idx & 7, k = idx >> 3;
    int seg = b*NID + k;
    int t = threadIdx.x;

    __shared__ unsigned int hc[NB], hg[NB];
    __shared__ unsigned int wbc[8], wbg[8], wexc[8], wexg[8];
    __shared__ float wsum[8];

    for (int i = t; i < NB; i += 512){
        unsigned long long v = 0ULL;
        for (int sp = 0; sp < S; sp++) v += part[((size_t)seg*S + sp)*NB + i];
        hc[i] = (unsigned int)(v >> 32);
        hg[i] = (unsigned int)(v & 0xffffffffULL);
    }
    __syncthreads();

    const int BPT = NB/512;      // 8
    int base = t*BPT;
    unsigned int c = 0, g = 0;
    #pragma unroll
    for (int i = 0; i < BPT; i++){
        int bin = NB-1 - (base+i);
        c += hc[bin]; g += hg[bin];
    }
    // wave inclusive scan (ascending t == descending bins)
    unsigned int ci = c, gi = g;
    int lane = t & 63, w = t >> 6;
    for (int o = 1; o < 64; o <<= 1){
        unsigned int cu = __shfl_up(ci, o);
        unsigned int gu = __shfl_up(gi, o);
        if (lane >= o){ ci += cu; gi += gu; }
    }
    if (lane == 63){ wbc[w] = ci; wbg[w] = gi; }
    __syncthreads();
    if (t == 0){
        unsigned int rc = 0, rg = 0;
        for (int i = 0; i < 8; i++){
            unsigned int a = wbc[i], bq = wbg[i];
            wexc[i] = rc; wexg[i] = rg;
            rc += a; rg += bq;
        }
    }
    __syncthreads();

    float G = stats[seg*4+0];
    float contrib = 0.0f;
    if (G > 0.0f){
        unsigned int n  = wexc[w] + (ci - c);
        unsigned int gg = wexg[w] + (gi - g);
        float jp = 0.0f;
        if (n > 0) jp = 1.0f - (G - (float)gg)/(G + (float)(n - gg));
        const float scale = 2.0f/(float)NB;
        #pragma unroll
        for (int i = 0; i < BPT; i++){
            int bin = NB-1 - (base+i);
            unsigned int cc = hc[bin], cg = hg[bin];
            if (cc | cg){
                n += cc; gg += cg;
                float j2 = 1.0f - (G - (float)gg)/(G + (float)(n - gg));
                contrib += ((float)bin + 0.5f)*scale*(j2 - jp);
                jp = j2;
            }
        }
    }
    for (int o = 32; o; o >>= 1) contrib += __shfl_xor(contrib, o);
    if ((t & 63) == 0) wsum[w] = contrib;
    __syncthreads();
    if (t == 0){
        float sres = 0.0f;
        for (int i = 0; i < 8; i++) sres += wsum[i];
        results[(size_t)seg*3 + 0] = sres;
    }
}

// ---- phase3b: var + seed_fg (pixel's own id only) ----
template<int PRE>
__global__ __launch_bounds__(256) void phase3b(const float* __restrict__ pred,
        const int* __restrict__ inst, const float* __restrict__ exy,
        const float* __restrict__ derived, float* __restrict__ results){
    int b = blockIdx.x >> 7;          // 128 blocks per image
    int base = (blockIdx.x & 127)*512;
    int t = threadIdx.x;
    __shared__ float scx[NID], scy[NID], ss[NID], ssm[NID];
    __shared__ float vacc[NID], sacc[NID];
    if (t < NID){
        const float* d0 = derived + (size_t)(b*NID + t)*4;
        scx[t] = d0[0]; scy[t] = d0[1]; ss[t] = d0[2]; ssm[t] = d0[3];
        vacc[t] = 0.0f; sacc[t] = 0.0f;
    }
    __syncthreads();

    const int Q = HWH/4;
    const float4* P = (const float4*)(pred + (size_t)b*6*HWH);
    const int4*   I = (const int4*)(inst + (size_t)b*HWH);
    const float4* EX = (const float4*)(exy + (size_t)b*2*HWH);
    const float4* EY = EX + Q;
    const float SC = 2.0f/511.0f;

    for (int it = 0; it < 2; ++it){
        int q = base + it*256 + t;
        float4 sg4 = P[2*Q+q], z54 = P[5*Q+q];
        int4 id4 = I[q];
        float4 ex4, ey4;
        if (PRE){ ex4 = EX[q]; ey4 = EY[q]; }
        else {
            float4 a = P[q], c = P[Q+q];
            int p = q*4;
            float gx = (float)(p & 511)*SC;
            float gy = (float)(p >> 9)*SC;
            ex4.x = ftanh(a.x)+gx;      ey4.x = ftanh(c.x)+gy;
            ex4.y = ftanh(a.y)+gx+SC;   ey4.y = ftanh(c.y)+gy;
            ex4.z = ftanh(a.z)+gx+2*SC; ey4.z = ftanh(c.z)+gy;
            ex4.w = ftanh(a.w)+gx+3*SC; ey4.w = ftanh(c.w)+gy;
        }
        auto px = [&](float ex, float ey, float sgv, float z5v, int id){
            if (id > 0){
                int kk = id - 1;
                float dx = ex - scx[kk], dy = ey - scy[kk];
                float d = __expf(-ss[kk]*(dx*dx + dy*dy));
                float seed = fsigmoid(z5v);
                float vd = sgv - ssm[kk];
                float sd = seed - d;
                atomicAdd(&vacc[kk], vd*vd);
                atomicAdd(&sacc[kk], sd*sd);
            }
        };
        px(ex4.x, ey4.x, sg4.x, z54.x, id4.x);
        px(ex4.y, ey4.y, sg4.y, z54.y, id4.y);
        px(ex4.z, ey4.z, sg4.z, z54.z, id4.z);
        px(ex4.w, ey4.w, sg4.w, z54.w, id4.w);
    }
    __syncthreads();
    if (t < NID){
        atomicAdd(&results[(size_t)(b*NID + t)*3 + 1], vacc[t]);
        atomicAdd(&results[(size_t)(b*NID + t)*3 + 2], sacc[t]);
    }
}

// ---------------- phase5: final combine ----------------
__global__ void phase5(const float* __restrict__ stats, const float* __restrict__ results,
                       const float* __restrict__ bgseed_p, const float* __restrict__ focal_p,
                       float* __restrict__ out){
    int t = threadIdx.x;   // 64
    float fs = focal_p[t] + focal_p[t+64] + focal_p[t+128] + focal_p[t+192];
    for (int o = 32; o; o >>= 1) fs += __shfl_xor(fs, o);
    __shared__ float per_b[BB];
    if (t < BB){
        float bs = 0.0f;
        for (int i = 0; i < 32; i++) bs += bgseed_p[t*32 + i];
        float nvalid = 0.0f, lsum = 0.0f, vsum = 0.0f, ssum = 0.0f;
        for (int k = 0; k < NID; k++){
            int seg = t*NID + k;
            float cnt = stats[seg*4+0];
            if (cnt > 0.0f){
                nvalid += 1.0f;
                lsum += results[seg*3+0];
                vsum += results[seg*3+1]/cnt;
                ssum += results[seg*3+2];
            }
        }
        float nobj = fmaxf(nvalid, 1.0f);
        per_b[t] = lsum/nobj + 10.0f*(vsum/nobj) + (bs + ssum)/(float)HWH;
    }
    __syncthreads();
    if (t == 0){
        float s = 0.0f;
        for (int b = 0; b < BB; b++) s += per_b[b];
        out[0] = s/(float)BB + fs/(float)(BB*HWH);
    }
}

extern "C" void kernel_launch(void* const* d_in, const int* in_sizes, int n_in,
                              void* d_out, int out_size, void* d_ws, size_t ws_size,
                              hipStream_t stream){
    const float* pred  = (const float*)d_in[0];
    const int*   labels= (const int*)d_in[1];
    const int*   inst  = (const int*)d_in[2];
    float* out = (float*)d_out;

    const size_t SMALL = 8192;
    const size_t EXYB  = (size_t)BB*2*HWH*4ull;     // 16.78 MB
    auto slab = [](int S){ return (size_t)NSEG*(size_t)S*NB*8ull; };

    int S; bool pre;
    if      (ws_size >= SMALL + slab(8) + EXYB){ S = 8; pre = true; }
    else if (ws_size >= SMALL + slab(4) + EXYB){ S = 4; pre = true; }
    else if (ws_size >= SMALL + slab(2) + EXYB){ S = 2; pre = true; }
    else if (ws_size >= SMALL + slab(8)){ S = 8; pre = false; }
    else if (ws_size >= SMALL + slab(4)){ S = 4; pre = false; }
    else if (ws_size >= SMALL + slab(2)){ S = 2; pre = false; }
    else { S = 1; pre = false; }

    float* stats    = (float*)d_ws;          // 480
    float* derived  = stats + NSEG*4;        // 480
    float* results  = derived + NSEG*4;      // 360
    float* bgseed_p = results + NSEG*3;      // 256
    float* focal_p  = bgseed_p + 256;        // 256
    unsigned long long* part = (unsigned long long*)((char*)d_ws + SMALL);
    float* exy = (float*)((char*)d_ws + SMALL + slab(S));

    hipLaunchKernelGGL(zero_small, dim3(1), dim3(512), 0, stream, stats, 1832);
    if (pre)
        phase1f<1><<<dim3(256), dim3(256), 0, stream>>>(pred, labels, inst, exy,
                                                        stats, bgseed_p, focal_p);
    else
        phase1f<0><<<dim3(256), dim3(256), 0, stream>>>(pred, labels, inst, exy,
                                                        stats, bgseed_p, focal_p);
    hipLaunchKernelGGL(phase2, dim3(1), dim3(128), 0, stream, stats, derived);
    if (pre)
        phaseLH<1><<<dim3(8*NID*S), dim3(512), 0, stream>>>(pred, inst, exy, derived, part, S);
    else
        phaseLH<0><<<dim3(8*NID*S), dim3(512), 0, stream>>>(pred, inst, exy, derived, part, S);
    hipLaunchKernelGGL(phaseLS, dim3(NSEG), dim3(512), 0, stream,
                       part, stats, results, S);
    if (pre)
        phase3b<1><<<dim3(BB*128), dim3(256), 0, stream>>>(pred, inst, exy, derived, results);
    else
        phase3b<0><<<dim3(BB*128), dim3(256), 0, stream>>>(pred, inst, exy, derived, results);
    hipLaunchKernelGGL(phase5, dim3(1), dim3(64), 0, stream,
                       stats, results, bgseed_p, focal_p, out);
}

// Round 4
// 125.238 us; speedup vs baseline: 13.0007x; 1.3759x over previous
//
#include <hip/hip_runtime.h>
#include <hip/hip_bf16.h>
#include <math.h>

#define BB 8
#define HWH (512*512)
#define NID 15
#define NSEG (BB*NID)
#define NB 4096
#define AA (4096.0f/13.0f)        // bins per unit log2(e), range log2(e) in [-12, 1]
#define LOG2E 1.442695041f

__device__ __forceinline__ float ftanh(float x){
    float t = __expf(2.0f*x);
    return 1.0f - 2.0f*__builtin_amdgcn_rcpf(t + 1.0f);
}
__device__ __forceinline__ float fsigmoid(float x){
    return __builtin_amdgcn_rcpf(1.0f + __expf(-x));
}

// ---------------- zero small accumulators ----------------
__global__ void zero_small(float* p, int n){
    for (int i = threadIdx.x; i < n; i += blockDim.x) p[i] = 0.0f;
}

// ---- phase1f: per-id stats (register acc), bg_seed, focal, + exy precompute ----
template<int PRE>
__global__ __launch_bounds__(256) void phase1f(const float* __restrict__ pred,
        const int* __restrict__ labels, const int* __restrict__ inst,
        float* __restrict__ exy, float* __restrict__ stats,
        float* __restrict__ bgseed_p, float* __restrict__ focal_p){
    int b = blockIdx.x >> 7;           // 128 blocks per image
    int chunk = blockIdx.x & 127;
    int t = threadIdx.x;

    float cnt[NID], sx[NID], sy[NID], ssg[NID];
    #pragma unroll
    for (int k = 0; k < NID; k++){ cnt[k]=0.f; sx[k]=0.f; sy[k]=0.f; ssg[k]=0.f; }
    float facc = 0.0f, bacc = 0.0f;

    const int Q = HWH/4;
    const float4* P = (const float4*)(pred + (size_t)b*6*HWH);
    const int4*   L = (const int4*)(labels + (size_t)b*3*HWH);
    const int4*   I = (const int4*)(inst + (size_t)b*HWH);
    float4* EX = (float4*)(exy + (size_t)b*2*HWH);
    float4* EY = EX + Q;
    const float SC = 2.0f/511.0f;

    #pragma unroll
    for (int it = 0; it < 2; ++it){
        int q = chunk*512 + it*256 + t;
        float4 sg4 = P[2*Q+q];
        float4 z3 = P[3*Q+q], z4 = P[4*Q+q], z5 = P[5*Q+q];
        int4 id4 = I[q];
        int4 l0 = L[q], l1 = L[Q+q], l2 = L[2*Q+q];
        int p = q*4;
        float gx = (float)(p & 511)*SC;
        float gy = (float)(p >> 9)*SC;
        if (PRE){
            float4 a = P[q], c = P[Q+q];
            float4 ex4, ey4;
            ex4.x = ftanh(a.x)+gx;        ey4.x = ftanh(c.x)+gy;
            ex4.y = ftanh(a.y)+gx+SC;     ey4.y = ftanh(c.y)+gy;
            ex4.z = ftanh(a.z)+gx+2*SC;   ey4.z = ftanh(c.z)+gy;
            ex4.w = ftanh(a.w)+gx+3*SC;   ey4.w = ftanh(c.w)+gy;
            EX[q] = ex4; EY[q] = ey4;
        }
        auto px = [&](float sgv, float z3v, float z4v, float z5v, int id,
                      int L0, int L1, int L2, float gxv){
            float seed = fsigmoid(z5v);
            if (L2 == 0) bacc += seed*seed;
            int tc = 0, best = L0;
            if (L1 > best){ tc = 1; best = L1; }
            if (L2 > best){ tc = 2; }
            float m = fmaxf(z3v, fmaxf(z4v, z5v));
            float e3 = __expf(z3v-m), e4 = __expf(z4v-m), e5 = __expf(z5v-m);
            float lse = m + __logf(e3+e4+e5);
            float zt = (tc==0) ? z3v : ((tc==1) ? z4v : z5v);
            float lp = zt - lse;
            float pt = __expf(lp);
            facc += -(1.0f-pt)*(1.0f-pt)*lp;
            #pragma unroll
            for (int k = 0; k < NID; k++){
                float msk = (id == k+1) ? 1.0f : 0.0f;
                cnt[k] += msk;
                sx[k]  = fmaf(msk, gxv, sx[k]);
                sy[k]  = fmaf(msk, gy,  sy[k]);
                ssg[k] = fmaf(msk, sgv, ssg[k]);
            }
        };
        px(sg4.x, z3.x, z4.x, z5.x, id4.x, l0.x, l1.x, l2.x, gx);
        px(sg4.y, z3.y, z4.y, z5.y, id4.y, l0.y, l1.y, l2.y, gx+SC);
        px(sg4.z, z3.z, z4.z, z5.z, id4.z, l0.z, l1.z, l2.z, gx+2*SC);
        px(sg4.w, z3.w, z4.w, z5.w, id4.w, l0.w, l1.w, l2.w, gx+3*SC);
    }

    // wave butterfly reduce
    #pragma unroll
    for (int k = 0; k < NID; k++){
        for (int o = 32; o; o >>= 1){
            cnt[k] += __shfl_xor(cnt[k], o);
            sx[k]  += __shfl_xor(sx[k],  o);
            sy[k]  += __shfl_xor(sy[k],  o);
            ssg[k] += __shfl_xor(ssg[k], o);
        }
    }
    for (int o = 32; o; o >>= 1){
        facc += __shfl_xor(facc, o);
        bacc += __shfl_xor(bacc, o);
    }

    // cross-wave combine in LDS, then 60 global atomics per block
    __shared__ float wst[4][NID*4];
    __shared__ float wfb[4][2];
    int w = t >> 6;
    if ((t & 63) == 0){
        #pragma unroll
        for (int k = 0; k < NID; k++){
            wst[w][k*4+0] = cnt[k];
            wst[w][k*4+1] = sx[k];
            wst[w][k*4+2] = sy[k];
            wst[w][k*4+3] = ssg[k];
        }
        wfb[w][0] = facc; wfb[w][1] = bacc;
    }
    __syncthreads();
    if (t < NID*4){
        float v = wst[0][t] + wst[1][t] + wst[2][t] + wst[3][t];
        atomicAdd(&stats[(size_t)b*NID*4 + t], v);
    }
    if (t == 0){
        focal_p[blockIdx.x]  = wfb[0][0]+wfb[1][0]+wfb[2][0]+wfb[3][0];
        bgseed_p[blockIdx.x] = wfb[0][1]+wfb[1][1]+wfb[2][1]+wfb[3][1];
    }
}

// ---------------- phase2: derive centers, s ----------------
__global__ void phase2(const float* __restrict__ stats, float* __restrict__ derived){
    int seg = blockIdx.x*blockDim.x + threadIdx.x;
    if (seg < NSEG){
        float cnt = stats[seg*4+0];
        float safe = fmaxf(cnt, 1.0f);
        derived[seg*4+0] = stats[seg*4+1]/safe;
        derived[seg*4+1] = stats[seg*4+2]/safe;
        float sm = stats[seg*4+3]/safe;
        derived[seg*4+2] = expf(10.0f*sm);
        derived[seg*4+3] = sm;
    }
}

// ---- phaseLH: per-(seg,slice) LDS histogram over log2(e) bins, slab writeback ----
template<int PRE>
__global__ __launch_bounds__(512) void phaseLH(const float* __restrict__ pred,
        const int* __restrict__ inst, const float* __restrict__ exy,
        const float* __restrict__ derived, unsigned long long* __restrict__ part,
        int S){
    int idx = blockIdx.x;
    int b = idx & 7;                 // XCD affinity: image b -> XCD b
    int j = idx >> 3;
    int k = j % NID;
    int sp = j / NID;
    int seg = b*NID + k;
    int t = threadIdx.x;

    __shared__ unsigned long long h8[NB];
    for (int i = t; i < NB; i += 512) h8[i] = 0ULL;
    float cx = derived[seg*4+0], cy = derived[seg*4+1], s = derived[seg*4+2];
    float Cs = LOG2E*AA*s;           // bg: binf = 4096 - Cs*r2
    __syncthreads();

    const int Q = HWH/4;
    int qps = Q / S;
    int q0 = sp * qps;
    const int4* I = (const int4*)(inst + (size_t)b*HWH);
    const float4* EX = (const float4*)(exy + (size_t)b*2*HWH);
    const float4* EY = EX + Q;
    const float4* P0 = (const float4*)(pred + (size_t)b*6*HWH);
    const float4* P1 = P0 + Q;
    const float SC = 2.0f/511.0f;
    const int kk = k + 1;

    auto px = [&](float ex, float ey, int id){
        float dx = ex - cx, dy = ey - cy;
        float r2 = fmaf(dx, dx, dy*dy);
        float binf_bg = fmaf(-Cs, r2, 4096.0f);
        float d = __expf(-s*r2);
        float e = fmaf(-2.0f, d, 2.0f);
        float binf_fg = fmaf(__log2f(e), AA, 4096.0f - AA);
        bool fg = (id == kk);
        float binf = fg ? binf_fg : binf_bg;
        binf = fminf(fmaxf(binf, 0.0f), 4095.0f);
        int bin = (int)binf;
        atomicAdd(&h8[bin], (1ULL << 32) | (fg ? 1ULL : 0ULL));
    };

    for (int q = q0 + t; q < q0 + qps; q += 512){
        int4 id4 = I[q];
        float4 ex4, ey4;
        if (PRE){ ex4 = EX[q]; ey4 = EY[q]; }
        else {
            float4 a = P0[q], c = P1[q];
            int p = q*4;
            float gx = (float)(p & 511)*SC;
            float gy = (float)(p >> 9)*SC;
            ex4.x = ftanh(a.x)+gx;      ey4.x = ftanh(c.x)+gy;
            ex4.y = ftanh(a.y)+gx+SC;   ey4.y = ftanh(c.y)+gy;
            ex4.z = ftanh(a.z)+gx+2*SC; ey4.z = ftanh(c.z)+gy;
            ex4.w = ftanh(a.w)+gx+3*SC; ey4.w = ftanh(c.w)+gy;
        }
        px(ex4.x, ey4.x, id4.x);
        px(ex4.y, ey4.y, id4.y);
        px(ex4.z, ey4.z, id4.z);
        px(ex4.w, ey4.w, id4.w);
    }
    __syncthreads();
    unsigned long long* dst = part + ((size_t)seg*S + sp)*NB;
    for (int i = t; i < NB; i += 512) dst[i] = h8[i];
}

// ---- phaseLS: merge slabs + descending Lovasz scan (wave-parallel) ----
__global__ __launch_bounds__(512) void phaseLS(const unsigned long long* __restrict__ part,
        const float* __restrict__ stats, float* __restrict__ results, int S){
    int idx = blockIdx.x;
    int b = idx & 7, k = idx >> 3;
    int seg = b*NID + k;
    int t = threadIdx.x;

    __shared__ unsigned int hc[NB], hg[NB];
    __shared__ unsigned int wbc[8], wbg[8], wexc[8], wexg[8];
    __shared__ float wsum[8];

    for (int i = t; i < NB; i += 512){
        unsigned long long v = 0ULL;
        for (int sp = 0; sp < S; sp++) v += part[((size_t)seg*S + sp)*NB + i];
        hc[i] = (unsigned int)(v >> 32);
        hg[i] = (unsigned int)(v & 0xffffffffULL);
    }
    __syncthreads();

    const int BPT = NB/512;
    int base = t*BPT;
    unsigned int c = 0, g = 0;
    #pragma unroll
    for (int i = 0; i < BPT; i++){
        int bin = NB-1 - (base+i);
        c += hc[bin]; g += hg[bin];
    }
    unsigned int ci = c, gi = g;
    int lane = t & 63, w = t >> 6;
    for (int o = 1; o < 64; o <<= 1){
        unsigned int cu = __shfl_up(ci, o);
        unsigned int gu = __shfl_up(gi, o);
        if (lane >= o){ ci += cu; gi += gu; }
    }
    if (lane == 63){ wbc[w] = ci; wbg[w] = gi; }
    __syncthreads();
    if (t == 0){
        unsigned int rc = 0, rg = 0;
        for (int i = 0; i < 8; i++){
            unsigned int a = wbc[i], bq = wbg[i];
            wexc[i] = rc; wexg[i] = rg;
            rc += a; rg += bq;
        }
    }
    __syncthreads();

    float G = stats[seg*4+0];
    float contrib = 0.0f;
    if (G > 0.0f){
        unsigned int n  = wexc[w] + (ci - c);
        unsigned int gg = wexg[w] + (gi - g);
        float jp = 0.0f;
        if (n > 0) jp = 1.0f - (G - (float)gg)/(G + (float)(n - gg));
        const float LN2 = 0.6931471806f;
        #pragma unroll
        for (int i = 0; i < BPT; i++){
            int bin = NB-1 - (base+i);
            unsigned int cc = hc[bin], cg = hg[bin];
            if (cc | cg){
                n += cc; gg += cg;
                float j2 = 1.0f - (G - (float)gg)/(G + (float)(n - gg));
                // bucket center in e-space: 2^((bin+0.5)/AA - 12)
                float ev = __expf(LN2*(((float)bin + 0.5f)*(13.0f/4096.0f) - 12.0f));
                contrib += ev*(j2 - jp);
                jp = j2;
            }
        }
    }
    for (int o = 32; o; o >>= 1) contrib += __shfl_xor(contrib, o);
    if ((t & 63) == 0) wsum[w] = contrib;
    __syncthreads();
    if (t == 0){
        float sres = 0.0f;
        for (int i = 0; i < 8; i++) sres += wsum[i];
        results[(size_t)seg*3 + 0] = sres;
    }
}

// ---- phase3b: var + seed_fg (pixel's own id only) ----
template<int PRE>
__global__ __launch_bounds__(256) void phase3b(const float* __restrict__ pred,
        const int* __restrict__ inst, const float* __restrict__ exy,
        const float* __restrict__ derived, float* __restrict__ results){
    int b = blockIdx.x >> 7;
    int base = (blockIdx.x & 127)*512;
    int t = threadIdx.x;
    __shared__ float scx[NID], scy[NID], ss[NID], ssm[NID];
    __shared__ float vacc[NID], sacc[NID];
    if (t < NID){
        const float* d0 = derived + (size_t)(b*NID + t)*4;
        scx[t] = d0[0]; scy[t] = d0[1]; ss[t] = d0[2]; ssm[t] = d0[3];
        vacc[t] = 0.0f; sacc[t] = 0.0f;
    }
    __syncthreads();

    const int Q = HWH/4;
    const float4* P = (const float4*)(pred + (size_t)b*6*HWH);
    const int4*   I = (const int4*)(inst + (size_t)b*HWH);
    const float4* EX = (const float4*)(exy + (size_t)b*2*HWH);
    const float4* EY = EX + Q;
    const float SC = 2.0f/511.0f;

    for (int it = 0; it < 2; ++it){
        int q = base + it*256 + t;
        float4 sg4 = P[2*Q+q], z54 = P[5*Q+q];
        int4 id4 = I[q];
        float4 ex4, ey4;
        if (PRE){ ex4 = EX[q]; ey4 = EY[q]; }
        else {
            float4 a = P[q], c = P[Q+q];
            int p = q*4;
            float gx = (float)(p & 511)*SC;
            float gy = (float)(p >> 9)*SC;
            ex4.x = ftanh(a.x)+gx;      ey4.x = ftanh(c.x)+gy;
            ex4.y = ftanh(a.y)+gx+SC;   ey4.y = ftanh(c.y)+gy;
            ex4.z = ftanh(a.z)+gx+2*SC; ey4.z = ftanh(c.z)+gy;
            ex4.w = ftanh(a.w)+gx+3*SC; ey4.w = ftanh(c.w)+gy;
        }
        auto px = [&](float ex, float ey, float sgv, float z5v, int id){
            if (id > 0){
                int kk = id - 1;
                float dx = ex - scx[kk], dy = ey - scy[kk];
                float d = __expf(-ss[kk]*(dx*dx + dy*dy));
                float seed = fsigmoid(z5v);
                float vd = sgv - ssm[kk];
                float sd = seed - d;
                atomicAdd(&vacc[kk], vd*vd);
                atomicAdd(&sacc[kk], sd*sd);
            }
        };
        px(ex4.x, ey4.x, sg4.x, z54.x, id4.x);
        px(ex4.y, ey4.y, sg4.y, z54.y, id4.y);
        px(ex4.z, ey4.z, sg4.z, z54.z, id4.z);
        px(ex4.w, ey4.w, sg4.w, z54.w, id4.w);
    }
    __syncthreads();
    if (t < NID){
        atomicAdd(&results[(size_t)(b*NID + t)*3 + 1], vacc[t]);
        atomicAdd(&results[(size_t)(b*NID + t)*3 + 2], sacc[t]);
    }
}

// ---------------- phase5: final combine ----------------
__global__ void phase5(const float* __restrict__ stats, const float* __restrict__ results,
                       const float* __restrict__ bgseed_p, const float* __restrict__ focal_p,
                       float* __restrict__ out){
    int t = threadIdx.x;   // 64
    float fs = 0.0f;
    for (int j = 0; j < 16; j++) fs += focal_p[t + 64*j];
    for (int o = 32; o; o >>= 1) fs += __shfl_xor(fs, o);
    __shared__ float per_b[BB];
    if (t < BB){
        float bs = 0.0f;
        for (int i = 0; i < 128; i++) bs += bgseed_p[t*128 + i];
        float nvalid = 0.0f, lsum = 0.0f, vsum = 0.0f, ssum = 0.0f;
        for (int k = 0; k < NID; k++){
            int seg = t*NID + k;
            float cnt = stats[seg*4+0];
            if (cnt > 0.0f){
                nvalid += 1.0f;
                lsum += results[seg*3+0];
                vsum += results[seg*3+1]/cnt;
                ssum += results[seg*3+2];
            }
        }
        float nobj = fmaxf(nvalid, 1.0f);
        per_b[t] = lsum/nobj + 10.0f*(vsum/nobj) + (bs + ssum)/(float)HWH;
    }
    __syncthreads();
    if (t == 0){
        float s = 0.0f;
        for (int b = 0; b < BB; b++) s += per_b[b];
        out[0] = s/(float)BB + fs/(float)(BB*HWH);
    }
}

extern "C" void kernel_launch(void* const* d_in, const int* in_sizes, int n_in,
                              void* d_out, int out_size, void* d_ws, size_t ws_size,
                              hipStream_t stream){
    const float* pred  = (const float*)d_in[0];
    const int*   labels= (const int*)d_in[1];
    const int*   inst  = (const int*)d_in[2];
    float* out = (float*)d_out;

    const size_t SMALL = 16384;
    const size_t EXYB  = (size_t)BB*2*HWH*4ull;
    auto slab = [](int S){ return (size_t)NSEG*(size_t)S*NB*8ull; };

    int S; bool pre;
    if      (ws_size >= SMALL + slab(8) + EXYB){ S = 8; pre = true; }
    else if (ws_size >= SMALL + slab(4) + EXYB){ S = 4; pre = true; }
    else if (ws_size >= SMALL + slab(2) + EXYB){ S = 2; pre = true; }
    else if (ws_size >= SMALL + slab(8)){ S = 8; pre = false; }
    else if (ws_size >= SMALL + slab(4)){ S = 4; pre = false; }
    else if (ws_size >= SMALL + slab(2)){ S = 2; pre = false; }
    else { S = 1; pre = false; }

    float* stats    = (float*)d_ws;          // 480
    float* derived  = stats + NSEG*4;        // 480
    float* results  = derived + NSEG*4;      // 360
    float* bgseed_p = results + NSEG*3;      // 1024
    float* focal_p  = bgseed_p + 1024;       // 1024
    unsigned long long* part = (unsigned long long*)((char*)d_ws + SMALL);
    float* exy = (float*)((char*)d_ws + SMALL + slab(S));

    hipLaunchKernelGGL(zero_small, dim3(1), dim3(512), 0, stream, stats, 1320);
    if (pre)
        phase1f<1><<<dim3(BB*128), dim3(256), 0, stream>>>(pred, labels, inst, exy,
                                                           stats, bgseed_p, focal_p);
    else
        phase1f<0><<<dim3(BB*128), dim3(256), 0, stream>>>(pred, labels, inst, exy,
                                                           stats, bgseed_p, focal_p);
    hipLaunchKernelGGL(phase2, dim3(1), dim3(128), 0, stream, stats, derived);
    if (pre)
        phaseLH<1><<<dim3(8*NID*S), dim3(512), 0, stream>>>(pred, inst, exy, derived, part, S);
    else
        phaseLH<0><<<dim3(8*NID*S), dim3(512), 0, stream>>>(pred, inst, exy, derived, part, S);
    hipLaunchKernelGGL(phaseLS, dim3(NSEG), dim3(512), 0, stream,
                       part, stats, results, S);
    if (pre)
        phase3b<1><<<dim3(BB*128), dim3(256), 0, stream>>>(pred, inst, exy, derived, results);
    else
        phase3b<0><<<dim3(BB*128), dim3(256), 0, stream>>>(pred, inst, exy, derived, results);
    hipLaunchKernelGGL(phase5, dim3(1), dim3(64), 0, stream,
                       stats, results, bgseed_p, focal_p, out);
}

// Round 5
// 124.595 us; speedup vs baseline: 13.0678x; 1.0052x over previous
//
#include <hip/hip_runtime.h>
#include <math.h>

#define BB 8
#define HWH (512*512)
#define NID 15
#define NSEG (BB*NID)
#define NBINS 2048
#define AAF ((float)NBINS/13.0f)
#define LOG2E 1.442695041f
#define LN2 0.6931471806f

__device__ __forceinline__ float ftanh(float x){
    float t = __expf(2.0f*x);
    return 1.0f - 2.0f*__builtin_amdgcn_rcpf(t + 1.0f);
}
__device__ __forceinline__ float fsigmoid(float x){
    return __builtin_amdgcn_rcpf(1.0f + __expf(-x));
}

// ---- phase1f: per-image-chunk stats via LDS atomics + focal/bgseed partials ----
__global__ __launch_bounds__(256) void phase1f(const float* __restrict__ pred,
        const int* __restrict__ labels, const int* __restrict__ inst,
        float* __restrict__ pstat, float* __restrict__ bgseed_p,
        float* __restrict__ focal_p){
    int blk = blockIdx.x;            // 2048 blocks, 256 per image
    int b = blk >> 8;
    int t = threadIdx.x;
    int q = (blk & 255)*256 + t;     // float4 index in image

    __shared__ float sstat[64];
    __shared__ float wfb[4][2];
    if (t < 64) sstat[t] = 0.0f;
    __syncthreads();

    const int Q = HWH/4;
    const float4* P = (const float4*)(pred + (size_t)b*6*HWH);
    const int4* L = (const int4*)(labels + (size_t)b*3*HWH);
    const int4* I = (const int4*)(inst + (size_t)b*HWH);
    float4 sg4 = P[2*Q+q], z3 = P[3*Q+q], z4 = P[4*Q+q], z5 = P[5*Q+q];
    int4 id4 = I[q];
    int4 l0 = L[q], l1 = L[Q+q], l2 = L[2*Q+q];
    const float SC = 2.0f/511.0f;
    int p = q*4;
    float gx = (float)(p & 511)*SC;
    float gy = (float)(p >> 9)*SC;

    float facc = 0.0f, bacc = 0.0f;
    auto px = [&](float sgv, float z3v, float z4v, float z5v, int id,
                  int L0, int L1, int L2, float gxv){
        float seed = fsigmoid(z5v);
        if (L2 == 0) bacc += seed*seed;
        int tc = 0, best = L0;
        if (L1 > best){ tc = 1; best = L1; }
        if (L2 > best){ tc = 2; }
        float m = fmaxf(z3v, fmaxf(z4v, z5v));
        float e3 = __expf(z3v-m), e4 = __expf(z4v-m), e5 = __expf(z5v-m);
        float sum = e3+e4+e5;
        float lse = m + __logf(sum);
        float zt = (tc==0) ? z3v : ((tc==1) ? z4v : z5v);
        float et = (tc==0) ? e3  : ((tc==1) ? e4  : e5);
        float lp = zt - lse;
        float pt = et*__builtin_amdgcn_rcpf(sum);
        float om = 1.0f - pt;
        facc -= om*om*lp;
        if (id > 0){
            float* sb = &sstat[(id-1)*4];
            atomicAdd(sb+0, 1.0f);
            atomicAdd(sb+1, gxv);
            atomicAdd(sb+2, gy);
            atomicAdd(sb+3, sgv);
        }
    };
    px(sg4.x, z3.x, z4.x, z5.x, id4.x, l0.x, l1.x, l2.x, gx);
    px(sg4.y, z3.y, z4.y, z5.y, id4.y, l0.y, l1.y, l2.y, gx+SC);
    px(sg4.z, z3.z, z4.z, z5.z, id4.z, l0.z, l1.z, l2.z, gx+2*SC);
    px(sg4.w, z3.w, z4.w, z5.w, id4.w, l0.w, l1.w, l2.w, gx+3*SC);

    for (int o = 32; o; o >>= 1){
        facc += __shfl_xor(facc, o);
        bacc += __shfl_xor(bacc, o);
    }
    if ((t & 63) == 0){ wfb[t>>6][0] = facc; wfb[t>>6][1] = bacc; }
    __syncthreads();
    if (t < 60) pstat[(size_t)blk*64 + t] = sstat[t];
    if (t == 0){
        focal_p[blk]  = wfb[0][0]+wfb[1][0]+wfb[2][0]+wfb[3][0];
        bgseed_p[blk] = wfb[0][1]+wfb[1][1]+wfb[2][1]+wfb[3][1];
    }
}

// ---- phaseR: reduce per-block partials -> stats, derived, focalR, bgseedR ----
__global__ __launch_bounds__(512) void phaseR(const float* __restrict__ pstat,
        const float* __restrict__ focal_p, const float* __restrict__ bgseed_p,
        float* __restrict__ stats, float* __restrict__ derived,
        float* __restrict__ focalR, float* __restrict__ bgseedR){
    int b = blockIdx.x;              // 8 blocks, one per image
    int t = threadIdx.x;
    int j = t & 63, chunk = t >> 6;  // 8 chunks x 32 blocks
    float acc = 0.0f;
    const float* base = pstat + (size_t)b*256*64;
    for (int i = 0; i < 32; i++)
        acc += base[(chunk*32 + i)*64 + j];
    __shared__ float red[8][64];
    __shared__ float st[64];
    red[chunk][j] = acc;
    __syncthreads();
    if (t < 64){
        float v = 0.0f;
        for (int c = 0; c < 8; c++) v += red[c][t];
        st[t] = v;
        if (t < 60) stats[b*60 + t] = v;
    }
    __syncthreads();
    if (t < NID){
        float cnt = st[t*4+0];
        float safe = fmaxf(cnt, 1.0f);
        float inv = 1.0f/safe;
        derived[(b*NID+t)*4+0] = st[t*4+1]*inv;
        derived[(b*NID+t)*4+1] = st[t*4+2]*inv;
        float sm = st[t*4+3]*inv;
        derived[(b*NID+t)*4+2] = __expf(10.0f*sm);
        derived[(b*NID+t)*4+3] = sm;
    }
    int w = t >> 6, lane = t & 63;
    if (w == 0){
        float f = focal_p[b*256 + lane] + focal_p[b*256 + 64 + lane]
                + focal_p[b*256 + 128 + lane] + focal_p[b*256 + 192 + lane];
        for (int o = 32; o; o >>= 1) f += __shfl_xor(f, o);
        if (lane == 0) focalR[b] = f;
    } else if (w == 1){
        float g = bgseed_p[b*256 + lane] + bgseed_p[b*256 + 64 + lane]
                + bgseed_p[b*256 + 128 + lane] + bgseed_p[b*256 + 192 + lane];
        for (int o = 32; o; o >>= 1) g += __shfl_xor(g, o);
        if (lane == 0) bgseedR[b] = g;
    }
}

// ---- phaseLH: per-(seg,slice) LDS log-histogram + fused var/seed accumulation ----
__global__ __launch_bounds__(512) void phaseLH(const float* __restrict__ pred,
        const int* __restrict__ inst, const float* __restrict__ derived,
        unsigned long long* __restrict__ part, float2* __restrict__ part2, int S){
    int idx = blockIdx.x;
    int b = idx & 7;                 // XCD affinity: image b -> XCD b
    int j = idx >> 3;
    int k = j % NID;
    int sp = j / NID;
    int seg = b*NID + k;
    int t = threadIdx.x;

    __shared__ unsigned long long h8[NBINS];
    __shared__ float vred[8][2];
    for (int i = t; i < NBINS; i += 512) h8[i] = 0ULL;
    float cx = derived[seg*4+0], cy = derived[seg*4+1], s = derived[seg*4+2];
    float sm = derived[seg*4+3];
    float Cs = LOG2E*AAF*s;
    __syncthreads();

    const int Q = HWH/4;
    int qps = Q / S;
    int q0 = sp * qps;
    const float* pb = pred + (size_t)b*6*HWH;
    const float4* P0 = (const float4*)pb;
    const float4* P1 = P0 + Q;
    const float* sgp = pb + 2*HWH;
    const float* z5p = pb + 5*HWH;
    const int4* I = (const int4*)(inst + (size_t)b*HWH);
    const float SC = 2.0f/511.0f;
    const int kk = k + 1;
    float vacc = 0.0f, sacc = 0.0f;

    for (int q = q0 + t; q < q0 + qps; q += 512){
        int4 id4 = I[q];
        float4 a = P0[q], c = P1[q];
        int p = q*4;
        float gx = (float)(p & 511)*SC;
        float gy = (float)(p >> 9)*SC;
        auto px = [&](float av, float cv, int id, float gxv, int pi){
            float ex = ftanh(av) + gxv;
            float ey = ftanh(cv) + gy;
            float dx = ex - cx, dy = ey - cy;
            float r2 = fmaf(dx, dx, dy*dy);
            bool fg = (id == kk);
            float binf;
            if (fg){
                float d = __expf(-s*r2);
                float e = fmaf(-2.0f, d, 2.0f);
                binf = fmaf(__log2f(e), AAF, (float)NBINS - AAF);
                float sgv = sgp[pi];
                float seed = fsigmoid(z5p[pi]);
                float vd = sgv - sm;
                float sd = seed - d;
                vacc = fmaf(vd, vd, vacc);
                sacc = fmaf(sd, sd, sacc);
            } else {
                binf = fmaf(-Cs, r2, (float)NBINS);
            }
            binf = fminf(fmaxf(binf, 0.0f), (float)(NBINS-1));
            int bin = (int)binf;
            atomicAdd(&h8[bin], (1ULL << 32) | (fg ? 1ULL : 0ULL));
        };
        px(a.x, c.x, id4.x, gx,      p);
        px(a.y, c.y, id4.y, gx+SC,   p+1);
        px(a.z, c.z, id4.z, gx+2*SC, p+2);
        px(a.w, c.w, id4.w, gx+3*SC, p+3);
    }
    for (int o = 32; o; o >>= 1){
        vacc += __shfl_xor(vacc, o);
        sacc += __shfl_xor(sacc, o);
    }
    if ((t & 63) == 0){ vred[t>>6][0] = vacc; vred[t>>6][1] = sacc; }
    __syncthreads();
    unsigned long long* dst = part + ((size_t)seg*S + sp)*NBINS;
    for (int i = t; i < NBINS; i += 512) dst[i] = h8[i];
    if (t == 0){
        float v = 0.0f, ss = 0.0f;
        for (int i2 = 0; i2 < 8; i2++){ v += vred[i2][0]; ss += vred[i2][1]; }
        part2[seg*S + sp] = make_float2(v, ss);
    }
}

// ---- phaseLS: merge slabs + descending Lovasz scan (wave-parallel) ----
__global__ __launch_bounds__(512) void phaseLS(const unsigned long long* __restrict__ part,
        const float2* __restrict__ part2, const float* __restrict__ stats,
        float* __restrict__ results, int S){
    int idx = blockIdx.x;
    int b = idx & 7, k = idx >> 3;
    int seg = b*NID + k;
    int t = threadIdx.x;

    __shared__ unsigned int hc[NBINS], hg[NBINS];
    __shared__ unsigned int wbc[8], wbg[8], wexc[8], wexg[8];
    __shared__ float wsum[8];

    for (int i = t; i < NBINS; i += 512){
        unsigned long long v = 0ULL;
        for (int sp = 0; sp < S; sp++) v += part[((size_t)seg*S + sp)*NBINS + i];
        hc[i] = (unsigned int)(v >> 32);
        hg[i] = (unsigned int)(v & 0xffffffffULL);
    }
    __syncthreads();

    const int BPT = NBINS/512;       // 4
    int base = t*BPT;
    unsigned int c = 0, g = 0;
    #pragma unroll
    for (int i = 0; i < BPT; i++){
        int bin = NBINS-1 - (base+i);
        c += hc[bin]; g += hg[bin];
    }
    unsigned int ci = c, gi = g;
    int lane = t & 63, w = t >> 6;
    for (int o = 1; o < 64; o <<= 1){
        unsigned int cu = __shfl_up(ci, o);
        unsigned int gu = __shfl_up(gi, o);
        if (lane >= o){ ci += cu; gi += gu; }
    }
    if (lane == 63){ wbc[w] = ci; wbg[w] = gi; }
    __syncthreads();
    if (t == 0){
        unsigned int rc = 0, rg = 0;
        for (int i = 0; i < 8; i++){
            unsigned int a = wbc[i], bq = wbg[i];
            wexc[i] = rc; wexg[i] = rg;
            rc += a; rg += bq;
        }
    }
    __syncthreads();

    float G = stats[b*60 + k*4 + 0];
    float contrib = 0.0f;
    if (G > 0.0f){
        unsigned int n  = wexc[w] + (ci - c);
        unsigned int gg = wexg[w] + (gi - g);
        float jp = 0.0f;
        if (n > 0) jp = 1.0f - (G - (float)gg)/(G + (float)(n - gg));
        #pragma unroll
        for (int i = 0; i < BPT; i++){
            int bin = NBINS-1 - (base+i);
            unsigned int cc = hc[bin], cg = hg[bin];
            if (cc | cg){
                n += cc; gg += cg;
                float j2 = 1.0f - (G - (float)gg)/(G + (float)(n - gg));
                float ev = __expf(LN2*(((float)bin + 0.5f)*(13.0f/(float)NBINS) - 12.0f));
                contrib += ev*(j2 - jp);
                jp = j2;
            }
        }
    }
    for (int o = 32; o; o >>= 1) contrib += __shfl_xor(contrib, o);
    if ((t & 63) == 0) wsum[w] = contrib;
    __syncthreads();
    if (t == 0){
        float sres = 0.0f;
        for (int i = 0; i < 8; i++) sres += wsum[i];
        results[(size_t)seg*3 + 0] = sres;
        float v = 0.0f, ss = 0.0f;
        for (int sp = 0; sp < S; sp++){
            float2 p2 = part2[seg*S + sp];
            v += p2.x; ss += p2.y;
        }
        results[(size_t)seg*3 + 1] = v;
        results[(size_t)seg*3 + 2] = ss;
    }
}

// ---------------- phase5: final combine ----------------
__global__ void phase5(const float* __restrict__ stats, const float* __restrict__ results,
                       const float* __restrict__ bgseedR, const float* __restrict__ focalR,
                       float* __restrict__ out){
    int t = threadIdx.x;
    __shared__ float per_b[BB];
    if (t < BB){
        float nvalid = 0.0f, lsum = 0.0f, vsum = 0.0f, ssum = 0.0f;
        for (int k = 0; k < NID; k++){
            int seg = t*NID + k;
            float cnt = stats[t*60 + k*4];
            if (cnt > 0.0f){
                nvalid += 1.0f;
                lsum += results[seg*3+0];
                vsum += results[seg*3+1]/cnt;
                ssum += results[seg*3+2];
            }
        }
        float nobj = fmaxf(nvalid, 1.0f);
        per_b[t] = lsum/nobj + 10.0f*(vsum/nobj) + (bgseedR[t] + ssum)/(float)HWH;
    }
    __syncthreads();
    if (t == 0){
        float s = 0.0f, fs = 0.0f;
        for (int b = 0; b < BB; b++){ s += per_b[b]; fs += focalR[b]; }
        out[0] = s/(float)BB + fs/(float)(BB*HWH);
    }
}

extern "C" void kernel_launch(void* const* d_in, const int* in_sizes, int n_in,
                              void* d_out, int out_size, void* d_ws, size_t ws_size,
                              hipStream_t stream){
    const float* pred  = (const float*)d_in[0];
    const int*   labels= (const int*)d_in[1];
    const int*   inst  = (const int*)d_in[2];
    float* out = (float*)d_out;

    // small-buffer sizes (floats)
    const size_t PSTAT_F = 2048*64;          // per-block stat partials
    const size_t SMALL_F = PSTAT_F + 2048 + 2048 + 480 + 480 + 360 + 8 + 8;
    auto need = [&](int S){
        return (size_t)NSEG*(size_t)S*NBINS*8ull          // hist slabs
             + (size_t)NSEG*(size_t)S*8ull                // var/seed partials
             + SMALL_F*4ull;
    };
    int S = 1;
    if      (ws_size >= need(8)) S = 8;
    else if (ws_size >= need(4)) S = 4;
    else if (ws_size >= need(2)) S = 2;

    unsigned long long* part = (unsigned long long*)d_ws;
    float2* part2 = (float2*)((char*)d_ws + (size_t)NSEG*(size_t)S*NBINS*8ull);
    float* pstat    = (float*)(part2 + (size_t)NSEG*S);
    float* focal_p  = pstat + PSTAT_F;
    float* bgseed_p = focal_p + 2048;
    float* stats    = bgseed_p + 2048;
    float* derived  = stats + 480;
    float* results  = derived + 480;
    float* focalR   = results + 360;
    float* bgseedR  = focalR + 8;

    hipLaunchKernelGGL(phase1f, dim3(2048), dim3(256), 0, stream,
                       pred, labels, inst, pstat, bgseed_p, focal_p);
    hipLaunchKernelGGL(phaseR, dim3(8), dim3(512), 0, stream,
                       pstat, focal_p, bgseed_p, stats, derived, focalR, bgseedR);
    hipLaunchKernelGGL(phaseLH, dim3(8*NID*S), dim3(512), 0, stream,
                       pred, inst, derived, part, part2, S);
    hipLaunchKernelGGL(phaseLS, dim3(NSEG), dim3(512), 0, stream,
                       part, part2, stats, results, S);
    hipLaunchKernelGGL(phase5, dim3(1), dim3(64), 0, stream,
                       stats, results, bgseedR, focalR, out);
}

// Round 6
// 96.119 us; speedup vs baseline: 16.9392x; 1.2963x over previous
//
#include <hip/hip_runtime.h>
#include <math.h>

#define BB 8
#define HWH (512*512)
#define NID 15
#define NSEG (BB*NID)
#define NBINS 1024
#define AAF ((float)NBINS/13.0f)
#define LOG2E 1.442695041f
#define LN2 0.6931471806f

typedef unsigned int uint32;
typedef unsigned long long uint64;

__device__ __forceinline__ float ftanh(float x){
    float t = __expf(2.0f*x);
    return 1.0f - 2.0f*__builtin_amdgcn_rcpf(t + 1.0f);
}
__device__ __forceinline__ float fsigmoid(float x){
    return __builtin_amdgcn_rcpf(1.0f + __expf(-x));
}

// ---- phase1f: per-chunk id-stats (packed u64 LDS atomics) + focal/bgseed partials ----
__global__ __launch_bounds__(256) void phase1f(const float* __restrict__ pred,
        const int* __restrict__ labels, const int* __restrict__ inst,
        uint64* __restrict__ pstat64, float* __restrict__ pstatf,
        float* __restrict__ bgseed_p, float* __restrict__ focal_p){
    int blk = blockIdx.x;            // 2048 blocks, 256 per image
    int b = blk >> 8;
    int t = threadIdx.x;
    int q = (blk & 255)*256 + t;     // float4 index in image

    __shared__ uint64 s64[NID];
    __shared__ float ssig[NID];
    __shared__ float wfb[4][2];
    if (t < NID){ s64[t] = 0ull; ssig[t] = 0.0f; }
    __syncthreads();

    const int Q = HWH/4;
    const float4* P = (const float4*)(pred + (size_t)b*6*HWH);
    const int4* L = (const int4*)(labels + (size_t)b*3*HWH);
    const int4* I = (const int4*)(inst + (size_t)b*HWH);
    float4 sg4 = P[2*Q+q], z3 = P[3*Q+q], z4 = P[4*Q+q], z5 = P[5*Q+q];
    int4 id4 = I[q];
    int4 l0 = L[q], l1 = L[Q+q], l2 = L[2*Q+q];
    int p = q*4;
    int w0 = p & 511, h0 = p >> 9;

    float facc = 0.0f, bacc = 0.0f;
    auto px = [&](float sgv, float z3v, float z4v, float z5v, int id,
                  int L0, int L1, int L2, int wv){
        float seed = fsigmoid(z5v);
        if (L2 == 0) bacc += seed*seed;
        int tc = 0, best = L0;
        if (L1 > best){ tc = 1; best = L1; }
        if (L2 > best){ tc = 2; }
        float m = fmaxf(z3v, fmaxf(z4v, z5v));
        float e3 = __expf(z3v-m), e4 = __expf(z4v-m), e5 = __expf(z5v-m);
        float sum = e3+e4+e5;
        float lse = m + __logf(sum);
        float zt = (tc==0) ? z3v : ((tc==1) ? z4v : z5v);
        float et = (tc==0) ? e3  : ((tc==1) ? e4  : e5);
        float lp = zt - lse;
        float pt = et*__builtin_amdgcn_rcpf(sum);
        float om = 1.0f - pt;
        facc -= om*om*lp;
        if (id > 0){
            atomicAdd(&s64[id-1],
                      (1ull<<42) | ((uint64)(uint32)wv<<21) | (uint64)(uint32)h0);
            atomicAdd(&ssig[id-1], sgv);
        }
    };
    px(sg4.x, z3.x, z4.x, z5.x, id4.x, l0.x, l1.x, l2.x, w0);
    px(sg4.y, z3.y, z4.y, z5.y, id4.y, l0.y, l1.y, l2.y, w0+1);
    px(sg4.z, z3.z, z4.z, z5.z, id4.z, l0.z, l1.z, l2.z, w0+2);
    px(sg4.w, z3.w, z4.w, z5.w, id4.w, l0.w, l1.w, l2.w, w0+3);

    for (int o = 32; o; o >>= 1){
        facc += __shfl_xor(facc, o);
        bacc += __shfl_xor(bacc, o);
    }
    if ((t & 63) == 0){ wfb[t>>6][0] = facc; wfb[t>>6][1] = bacc; }
    __syncthreads();
    if (t < NID){
        pstat64[blk*16 + t] = s64[t];
        pstatf [blk*16 + t] = ssig[t];
    }
    if (t == 0){
        focal_p[blk]  = wfb[0][0]+wfb[1][0]+wfb[2][0]+wfb[3][0];
        bgseed_p[blk] = wfb[0][1]+wfb[1][1]+wfb[2][1]+wfb[3][1];
    }
}

// ---- phaseR: reduce partials -> stats(cnt), derived, focalR, bgseedR ----
__global__ __launch_bounds__(512) void phaseR(const uint64* __restrict__ pstat64,
        const float* __restrict__ pstatf,
        const float* __restrict__ focal_p, const float* __restrict__ bgseed_p,
        float* __restrict__ stats, float* __restrict__ derived,
        float* __restrict__ focalR, float* __restrict__ bgseedR){
    int b = blockIdx.x;              // 8 blocks
    int t = threadIdx.x;
    int k = t & 15, chunk = t >> 4;  // 32 chunks x 8 partial-blocks
    float acnt = 0, asw = 0, ash = 0, af = 0;
    for (int i = 0; i < 8; i++){
        int blk = b*256 + chunk*8 + i;
        uint64 v = pstat64[blk*16 + k];
        acnt += (float)(uint32)(v >> 42);
        asw  += (float)(uint32)((v >> 21) & 0x1FFFFF);
        ash  += (float)(uint32)(v & 0x1FFFFF);
        af   += pstatf[blk*16 + k];
    }
    __shared__ float tc[16], tw[16], th[16], ts[16];
    if (t < 16){ tc[t]=0; tw[t]=0; th[t]=0; ts[t]=0; }
    __syncthreads();
    atomicAdd(&tc[k], acnt);
    atomicAdd(&tw[k], asw);
    atomicAdd(&th[k], ash);
    atomicAdd(&ts[k], af);
    __syncthreads();
    if (t < NID){
        float cnt = tc[t];
        float safe = fmaxf(cnt, 1.0f);
        float inv = 1.0f/safe;
        const float SC = 2.0f/511.0f;
        derived[(b*NID+t)*4+0] = tw[t]*SC*inv;
        derived[(b*NID+t)*4+1] = th[t]*SC*inv;
        float sm = ts[t]*inv;
        derived[(b*NID+t)*4+2] = __expf(10.0f*sm);
        derived[(b*NID+t)*4+3] = sm;
        stats[b*60 + t*4] = cnt;
    }
    int w = t >> 6, lane = t & 63;
    if (w == 0){
        float f = 0;
        for (int j = 0; j < 4; j++) f += focal_p[b*256 + j*64 + lane];
        for (int o = 32; o; o >>= 1) f += __shfl_xor(f, o);
        if (lane == 0) focalR[b] = f;
    } else if (w == 1){
        float g = 0;
        for (int j = 0; j < 4; j++) g += bgseed_p[b*256 + j*64 + lane];
        for (int o = 32; o; o >>= 1) g += __shfl_xor(g, o);
        if (lane == 0) bgseedR[b] = g;
    }
}

// ---- phaseLH: one block = one pixel-slice, ALL 15 segments; 15 LDS histograms ----
__global__ __launch_bounds__(512) void phaseLH(const float* __restrict__ pred,
        const int* __restrict__ inst, const float* __restrict__ derived,
        uint32* __restrict__ part, float2* __restrict__ part2, int S){
    int idx = blockIdx.x;
    int b = idx & 7;                 // XCD affinity
    int sp = idx >> 3;
    int t = threadIdx.x;

    __shared__ uint32 hist[NID*NBINS];          // (count<<16)|fg
    __shared__ float scx[NID], scy[NID], ssl[NID], ssm[NID], sCs[NID];
    __shared__ float vsA[NID], vsB[NID];
    for (int i = t; i < NID*NBINS; i += 512) hist[i] = 0u;
    if (t < NID){
        const float* d0 = derived + (size_t)(b*NID + t)*4;
        scx[t] = d0[0]; scy[t] = d0[1]; ssl[t] = d0[2]; ssm[t] = d0[3];
        sCs[t] = LOG2E*AAF*d0[2];
        vsA[t] = 0.0f; vsB[t] = 0.0f;
    }
    __syncthreads();

    const int Q = HWH/4;
    int qps = Q / S;
    int q0 = sp * qps;
    const float* pb = pred + (size_t)b*6*HWH;
    const float4* P0 = (const float4*)pb;
    const float4* P1 = P0 + Q;
    const float4* P2 = P0 + 2*Q;
    const float4* P5 = P0 + 5*Q;
    const int4* I = (const int4*)(inst + (size_t)b*HWH);
    const float SC = 2.0f/511.0f;

    for (int q = q0 + t; q < q0 + qps; q += 512){
        int4 id4 = I[q];
        float4 a = P0[q], c = P1[q], sg4 = P2[q], z54 = P5[q];
        int p = q*4;
        float gx = (float)(p & 511)*SC;
        float gy = (float)(p >> 9)*SC;
        auto px = [&](float av, float cv, float sgv, float z5v, int id, float gxv){
            float ex = ftanh(av) + gxv;
            float ey = ftanh(cv) + gy;
            int own = id - 1;
            float r2own = 0.0f;
            #pragma unroll
            for (int k = 0; k < NID; k++){
                float dx = ex - scx[k], dy = ey - scy[k];
                float r2 = fmaf(dx, dx, dy*dy);
                if (k == own) r2own = r2;                 // cndmask, no branch
                float binf = fmaf(-sCs[k], r2, (float)NBINS);
                binf = fminf(fmaxf(binf, 0.0f), (float)(NBINS-1));
                atomicAdd(&hist[k*NBINS + (int)binf], 65536u);
            }
            if (own >= 0){
                float d = __expf(-ssl[own]*r2own);
                float e = fmaf(-2.0f, d, 2.0f);
                float bf = fmaf(__log2f(e), AAF, (float)NBINS - AAF);
                bf = fminf(fmaxf(bf, 0.0f), (float)(NBINS-1));
                float bb = fmaf(-sCs[own], r2own, (float)NBINS);
                bb = fminf(fmaxf(bb, 0.0f), (float)(NBINS-1));
                atomicAdd(&hist[own*NBINS + (int)bb], 0xFFFF0000u); // undo bg
                atomicAdd(&hist[own*NBINS + (int)bf], 65537u);      // fg entry
                float seed = fsigmoid(z5v);
                float vd = sgv - ssm[own];
                float sd = seed - d;
                atomicAdd(&vsA[own], vd*vd);
                atomicAdd(&vsB[own], sd*sd);
            }
        };
        px(a.x, c.x, sg4.x, z54.x, id4.x, gx);
        px(a.y, c.y, sg4.y, z54.y, id4.y, gx+SC);
        px(a.z, c.z, sg4.z, z54.z, id4.z, gx+2*SC);
        px(a.w, c.w, sg4.w, z54.w, id4.w, gx+3*SC);
    }
    __syncthreads();
    uint32* dst = part + ((size_t)(b*S + sp))*NID*NBINS;
    for (int i = t; i < NID*NBINS; i += 512) dst[i] = hist[i];
    if (t < NID) part2[(size_t)(b*S + sp)*NID + t] = make_float2(vsA[t], vsB[t]);
}

// ---- phaseLS: merge slices + descending Lovasz scan ----
__global__ __launch_bounds__(512) void phaseLS(const uint32* __restrict__ part,
        const float2* __restrict__ part2, const float* __restrict__ stats,
        float* __restrict__ results, int S){
    int idx = blockIdx.x;            // 120 = (b in low 3 bits for XCD match)
    int b = idx & 7, k = idx >> 3;
    int seg = b*NID + k;
    int t = threadIdx.x;

    __shared__ uint32 hc[NBINS], hg[NBINS];
    __shared__ uint32 wbc[8], wbg[8], wexc[8], wexg[8];
    __shared__ float wsum[8];

    for (int i = t; i < NBINS; i += 512){
        uint32 c = 0, g = 0;
        for (int sp = 0; sp < S; sp++){
            uint32 v = part[((size_t)(b*S + sp)*NID + k)*NBINS + i];
            c += v >> 16; g += v & 0xFFFFu;
        }
        hc[i] = c; hg[i] = g;
    }
    __syncthreads();

    const int BPT = NBINS/512;       // 2
    int base = t*BPT;
    uint32 c = 0, g = 0;
    #pragma unroll
    for (int i = 0; i < BPT; i++){
        int bin = NBINS-1 - (base+i);
        c += hc[bin]; g += hg[bin];
    }
    uint32 ci = c, gi = g;
    int lane = t & 63, w = t >> 6;
    for (int o = 1; o < 64; o <<= 1){
        uint32 cu = __shfl_up(ci, o);
        uint32 gu = __shfl_up(gi, o);
        if (lane >= o){ ci += cu; gi += gu; }
    }
    if (lane == 63){ wbc[w] = ci; wbg[w] = gi; }
    __syncthreads();
    if (t == 0){
        uint32 rc = 0, rg = 0;
        for (int i = 0; i < 8; i++){
            uint32 a = wbc[i], bq = wbg[i];
            wexc[i] = rc; wexg[i] = rg;
            rc += a; rg += bq;
        }
    }
    __syncthreads();

    float G = stats[b*60 + k*4];
    float contrib = 0.0f;
    if (G > 0.0f){
        uint32 n  = wexc[w] + (ci - c);
        uint32 gg = wexg[w] + (gi - g);
        float jp = 0.0f;
        if (n > 0) jp = 1.0f - (G - (float)gg)/(G + (float)(n - gg));
        #pragma unroll
        for (int i = 0; i < BPT; i++){
            int bin = NBINS-1 - (base+i);
            uint32 cc = hc[bin], cg = hg[bin];
            if (cc | cg){
                n += cc; gg += cg;
                float j2 = 1.0f - (G - (float)gg)/(G + (float)(n - gg));
                float ev = __expf(LN2*(((float)bin + 0.5f)*(13.0f/(float)NBINS) - 12.0f));
                contrib += ev*(j2 - jp);
                jp = j2;
            }
        }
    }
    for (int o = 32; o; o >>= 1) contrib += __shfl_xor(contrib, o);
    if ((t & 63) == 0) wsum[w] = contrib;
    __syncthreads();
    if (t == 0){
        float sres = 0.0f;
        for (int i = 0; i < 8; i++) sres += wsum[i];
        results[(size_t)seg*3 + 0] = sres;
    }
    // var/seed partial sums: wave 1
    if (w == 1){
        float v = 0.0f, ss = 0.0f;
        for (int sp = lane; sp < S; sp += 64){
            float2 p2 = part2[(size_t)(b*S + sp)*NID + k];
            v += p2.x; ss += p2.y;
        }
        for (int o = 32; o; o >>= 1){
            v += __shfl_xor(v, o);
            ss += __shfl_xor(ss, o);
        }
        if (lane == 0){
            results[(size_t)seg*3 + 1] = v;
            results[(size_t)seg*3 + 2] = ss;
        }
    }
}

// ---------------- phase5: final combine ----------------
__global__ void phase5(const float* __restrict__ stats, const float* __restrict__ results,
                       const float* __restrict__ bgseedR, const float* __restrict__ focalR,
                       float* __restrict__ out){
    int t = threadIdx.x;
    __shared__ float per_b[BB];
    if (t < BB){
        float nvalid = 0.0f, lsum = 0.0f, vsum = 0.0f, ssum = 0.0f;
        for (int k = 0; k < NID; k++){
            int seg = t*NID + k;
            float cnt = stats[t*60 + k*4];
            if (cnt > 0.0f){
                nvalid += 1.0f;
                lsum += results[seg*3+0];
                vsum += results[seg*3+1]/cnt;
                ssum += results[seg*3+2];
            }
        }
        float nobj = fmaxf(nvalid, 1.0f);
        per_b[t] = lsum/nobj + 10.0f*(vsum/nobj) + (bgseedR[t] + ssum)/(float)HWH;
    }
    __syncthreads();
    if (t == 0){
        float s = 0.0f, fs = 0.0f;
        for (int b = 0; b < BB; b++){ s += per_b[b]; fs += focalR[b]; }
        out[0] = s/(float)BB + fs/(float)(BB*HWH);
    }
}

extern "C" void kernel_launch(void* const* d_in, const int* in_sizes, int n_in,
                              void* d_out, int out_size, void* d_ws, size_t ws_size,
                              hipStream_t stream){
    const float* pred  = (const float*)d_in[0];
    const int*   labels= (const int*)d_in[1];
    const int*   inst  = (const int*)d_in[2];
    float* out = (float*)d_out;

    auto need = [](int S){
        return (size_t)BB*S*NID*NBINS*4ull       // hist slabs (u32)
             + (size_t)BB*S*NID*8ull             // var/seed partials (float2)
             + 2048ull*16*8 + 2048ull*16*4       // pstat64 + pstatf
             + 2048ull*4*2                        // focal_p, bgseed_p
             + (480+480+360+8+8)*4ull;
    };
    int S = 8;
    if      (ws_size >= need(64)) S = 64;
    else if (ws_size >= need(32)) S = 32;
    else if (ws_size >= need(16)) S = 16;

    uint32* part   = (uint32*)d_ws;
    float2* part2  = (float2*)((char*)d_ws + (size_t)BB*S*NID*NBINS*4ull);
    uint64* pstat64= (uint64*)(part2 + (size_t)BB*S*NID);
    float* pstatf  = (float*)(pstat64 + 2048*16);
    float* focal_p = pstatf + 2048*16;
    float* bgseed_p= focal_p + 2048;
    float* stats   = bgseed_p + 2048;
    float* derived = stats + 480;
    float* results = derived + 480;
    float* focalR  = results + 360;
    float* bgseedR = focalR + 8;

    hipLaunchKernelGGL(phase1f, dim3(2048), dim3(256), 0, stream,
                       pred, labels, inst, pstat64, pstatf, bgseed_p, focal_p);
    hipLaunchKernelGGL(phaseR, dim3(8), dim3(512), 0, stream,
                       pstat64, pstatf, focal_p, bgseed_p, stats, derived, focalR, bgseedR);
    hipLaunchKernelGGL(phaseLH, dim3(BB*S), dim3(512), 0, stream,
                       pred, inst, derived, part, part2, S);
    hipLaunchKernelGGL(phaseLS, dim3(NSEG), dim3(512), 0, stream,
                       part, part2, stats, results, S);
    hipLaunchKernelGGL(phase5, dim3(1), dim3(64), 0, stream,
                       stats, results, bgseedR, focalR, out);
}

// Round 7
// 94.881 us; speedup vs baseline: 17.1603x; 1.0131x over previous
//
#include <hip/hip_runtime.h>
#include <math.h>

#define BB 8
#define HWH (512*512)
#define NID 15
#define NSEG (BB*NID)
#define NBINS 1024
#define AAF ((float)NBINS/13.0f)
#define LOG2E 1.442695041f
#define LN2 0.6931471806f
#define KG 8

typedef unsigned int uint32;
typedef unsigned long long uint64;

__device__ __forceinline__ float ftanh(float x){
    float t = __expf(2.0f*x);
    return 1.0f - 2.0f*__builtin_amdgcn_rcpf(t + 1.0f);
}
__device__ __forceinline__ float fsigmoid(float x){
    return __builtin_amdgcn_rcpf(1.0f + __expf(-x));
}

// ---- phase1f: per-chunk id-stats (packed u64 LDS atomics) + focal/bgseed partials ----
__global__ __launch_bounds__(256, 8) void phase1f(const float* __restrict__ pred,
        const int* __restrict__ labels, const int* __restrict__ inst,
        uint64* __restrict__ pstat64, float* __restrict__ pstatf,
        float* __restrict__ bgseed_p, float* __restrict__ focal_p){
    int blk = blockIdx.x;            // 2048 blocks, 256 per image
    int b = blk >> 8;
    int t = threadIdx.x;
    int q = (blk & 255)*256 + t;     // float4 index in image

    __shared__ uint64 s64[NID];
    __shared__ float ssig[NID];
    __shared__ float wfb[4][2];
    if (t < NID){ s64[t] = 0ull; ssig[t] = 0.0f; }
    __syncthreads();

    const int Q = HWH/4;
    const float4* P = (const float4*)(pred + (size_t)b*6*HWH);
    const int4* L = (const int4*)(labels + (size_t)b*3*HWH);
    const int4* I = (const int4*)(inst + (size_t)b*HWH);
    float4 sg4 = P[2*Q+q], z3 = P[3*Q+q], z4 = P[4*Q+q], z5 = P[5*Q+q];
    int4 id4 = I[q];
    int4 l0 = L[q], l1 = L[Q+q], l2 = L[2*Q+q];
    int p = q*4;
    int w0 = p & 511, h0 = p >> 9;

    float facc = 0.0f, bacc = 0.0f;
    auto px = [&](float sgv, float z3v, float z4v, float z5v, int id,
                  int L0, int L1, int L2, int wv){
        float seed = fsigmoid(z5v);
        if (L2 == 0) bacc += seed*seed;
        int tc = 0, best = L0;
        if (L1 > best){ tc = 1; best = L1; }
        if (L2 > best){ tc = 2; }
        float m = fmaxf(z3v, fmaxf(z4v, z5v));
        float e3 = __expf(z3v-m), e4 = __expf(z4v-m), e5 = __expf(z5v-m);
        float sum = e3+e4+e5;
        float lse = m + __logf(sum);
        float zt = (tc==0) ? z3v : ((tc==1) ? z4v : z5v);
        float et = (tc==0) ? e3  : ((tc==1) ? e4  : e5);
        float lp = zt - lse;
        float pt = et*__builtin_amdgcn_rcpf(sum);
        float om = 1.0f - pt;
        facc -= om*om*lp;
        if (id > 0){
            atomicAdd(&s64[id-1],
                      (1ull<<42) | ((uint64)(uint32)wv<<21) | (uint64)(uint32)h0);
            atomicAdd(&ssig[id-1], sgv);
        }
    };
    px(sg4.x, z3.x, z4.x, z5.x, id4.x, l0.x, l1.x, l2.x, w0);
    px(sg4.y, z3.y, z4.y, z5.y, id4.y, l0.y, l1.y, l2.y, w0+1);
    px(sg4.z, z3.z, z4.z, z5.z, id4.z, l0.z, l1.z, l2.z, w0+2);
    px(sg4.w, z3.w, z4.w, z5.w, id4.w, l0.w, l1.w, l2.w, w0+3);

    for (int o = 32; o; o >>= 1){
        facc += __shfl_xor(facc, o);
        bacc += __shfl_xor(bacc, o);
    }
    if ((t & 63) == 0){ wfb[t>>6][0] = facc; wfb[t>>6][1] = bacc; }
    __syncthreads();
    if (t < NID){
        pstat64[blk*16 + t] = s64[t];
        pstatf [blk*16 + t] = ssig[t];
    }
    if (t == 0){
        focal_p[blk]  = wfb[0][0]+wfb[1][0]+wfb[2][0]+wfb[3][0];
        bgseed_p[blk] = wfb[0][1]+wfb[1][1]+wfb[2][1]+wfb[3][1];
    }
}

// ---- phaseR: reduce partials -> stats(cnt), derived, focalR, bgseedR ----
__global__ __launch_bounds__(512) void phaseR(const uint64* __restrict__ pstat64,
        const float* __restrict__ pstatf,
        const float* __restrict__ focal_p, const float* __restrict__ bgseed_p,
        float* __restrict__ stats, float* __restrict__ derived,
        float* __restrict__ focalR, float* __restrict__ bgseedR){
    int b = blockIdx.x;              // 8 blocks
    int t = threadIdx.x;
    int k = t & 15, chunk = t >> 4;  // 32 chunks x 8 partial-blocks
    float acnt = 0, asw = 0, ash = 0, af = 0;
    for (int i = 0; i < 8; i++){
        int blk = b*256 + chunk*8 + i;
        uint64 v = pstat64[blk*16 + k];
        acnt += (float)(uint32)(v >> 42);
        asw  += (float)(uint32)((v >> 21) & 0x1FFFFF);
        ash  += (float)(uint32)(v & 0x1FFFFF);
        af   += pstatf[blk*16 + k];
    }
    __shared__ float tc[16], tw[16], th[16], ts[16];
    if (t < 16){ tc[t]=0; tw[t]=0; th[t]=0; ts[t]=0; }
    __syncthreads();
    atomicAdd(&tc[k], acnt);
    atomicAdd(&tw[k], asw);
    atomicAdd(&th[k], ash);
    atomicAdd(&ts[k], af);
    __syncthreads();
    if (t < NID){
        float cnt = tc[t];
        float safe = fmaxf(cnt, 1.0f);
        float inv = 1.0f/safe;
        const float SC = 2.0f/511.0f;
        derived[(b*NID+t)*4+0] = tw[t]*SC*inv;
        derived[(b*NID+t)*4+1] = th[t]*SC*inv;
        float sm = ts[t]*inv;
        derived[(b*NID+t)*4+2] = __expf(10.0f*sm);
        derived[(b*NID+t)*4+3] = sm;
        stats[b*60 + t*4] = cnt;
    }
    int w = t >> 6, lane = t & 63;
    if (w == 0){
        float f = 0;
        for (int j = 0; j < 4; j++) f += focal_p[b*256 + j*64 + lane];
        for (int o = 32; o; o >>= 1) f += __shfl_xor(f, o);
        if (lane == 0) focalR[b] = f;
    } else if (w == 1){
        float g = 0;
        for (int j = 0; j < 4; j++) g += bgseed_p[b*256 + j*64 + lane];
        for (int o = 32; o; o >>= 1) g += __shfl_xor(g, o);
        if (lane == 0) bgseedR[b] = g;
    }
}

// ---- phaseLH: one block = (pixel-slice, k-group of 8); 8 LDS histograms ----
__global__ __launch_bounds__(512, 8) void phaseLH(const float* __restrict__ pred,
        const int* __restrict__ inst, const float* __restrict__ derived,
        uint32* __restrict__ part, float2* __restrict__ part2, int S){
    int idx = blockIdx.x;
    int b = idx & 7;                 // XCD affinity
    int sp = (idx >> 3) & (S - 1);
    int kg = idx >> 3 >> __popc(S - 1);     // 0 or 1
    int kbase = kg*KG;
    int kcnt = kg ? (NID - KG) : KG;        // 7 or 8
    int t = threadIdx.x;

    __shared__ uint32 hist[KG*NBINS];       // (count<<16)|fg
    __shared__ float scx[KG], scy[KG], ssl[KG], ssm[KG], sCs[KG];
    __shared__ float vsA[KG], vsB[KG];
    for (int i = t; i < KG*NBINS; i += 512) hist[i] = 0u;
    if (t < kcnt){
        const float* d0 = derived + (size_t)(b*NID + kbase + t)*4;
        scx[t] = d0[0]; scy[t] = d0[1]; ssl[t] = d0[2]; ssm[t] = d0[3];
        sCs[t] = LOG2E*AAF*d0[2];
        vsA[t] = 0.0f; vsB[t] = 0.0f;
    }
    __syncthreads();

    const int Q = HWH/4;
    int qps = Q / S;
    int q0 = sp * qps;
    const float* pb = pred + (size_t)b*6*HWH;
    const float4* P0 = (const float4*)pb;
    const float4* P1 = P0 + Q;
    const float* sgp = pb + 2*HWH;
    const float* z5p = pb + 5*HWH;
    const int4* I = (const int4*)(inst + (size_t)b*HWH);
    const float SC = 2.0f/511.0f;

    for (int q = q0 + t; q < q0 + qps; q += 512){
        int4 id4 = I[q];
        float4 a = P0[q], c = P1[q];
        int p = q*4;
        float gx = (float)(p & 511)*SC;
        float gy = (float)(p >> 9)*SC;
        auto px = [&](float av, float cv, int id, float gxv, int pi){
            float ex = ftanh(av) + gxv;
            float ey = ftanh(cv) + gy;
            int own = id - 1 - kbase;            // local index if in this k-group
            float r2own = 0.0f;
            #pragma unroll
            for (int j = 0; j < KG; j++){
                if (j < kcnt){
                    float dx = ex - scx[j], dy = ey - scy[j];
                    float r2 = fmaf(dx, dx, dy*dy);
                    if (j == own) r2own = r2;    // cndmask, no branch
                    float binf = fmaf(-sCs[j], r2, (float)NBINS);
                    binf = fminf(fmaxf(binf, 0.0f), (float)(NBINS-1));
                    atomicAdd(&hist[j*NBINS + (int)binf], 65536u);
                }
            }
            if (own >= 0 && own < kcnt){
                float d = __expf(-ssl[own]*r2own);
                float e = fmaf(-2.0f, d, 2.0f);
                float bf = fmaf(__log2f(e), AAF, (float)NBINS - AAF);
                bf = fminf(fmaxf(bf, 0.0f), (float)(NBINS-1));
                float bb = fmaf(-sCs[own], r2own, (float)NBINS);
                bb = fminf(fmaxf(bb, 0.0f), (float)(NBINS-1));
                atomicAdd(&hist[own*NBINS + (int)bb], 0xFFFF0000u); // undo bg
                atomicAdd(&hist[own*NBINS + (int)bf], 65537u);      // fg entry
                float sgv = sgp[pi];
                float seed = fsigmoid(z5p[pi]);
                float vd = sgv - ssm[own];
                float sd = seed - d;
                atomicAdd(&vsA[own], vd*vd);
                atomicAdd(&vsB[own], sd*sd);
            }
        };
        px(a.x, c.x, id4.x, gx,      p);
        px(a.y, c.y, id4.y, gx+SC,   p+1);
        px(a.z, c.z, id4.z, gx+2*SC, p+2);
        px(a.w, c.w, id4.w, gx+3*SC, p+3);
    }
    __syncthreads();
    uint32* dst = part + ((size_t)(b*S + sp)*NID + kbase)*NBINS;
    for (int i = t; i < kcnt*NBINS; i += 512) dst[i] = hist[i];
    if (t < kcnt) part2[(size_t)(b*S + sp)*NID + kbase + t] = make_float2(vsA[t], vsB[t]);
}

// ---- phaseLS: merge slices + descending Lovasz scan ----
__global__ __launch_bounds__(512) void phaseLS(const uint32* __restrict__ part,
        const float2* __restrict__ part2, const float* __restrict__ stats,
        float* __restrict__ results, int S){
    int idx = blockIdx.x;            // 120
    int b = idx & 7, k = idx >> 3;
    int seg = b*NID + k;
    int t = threadIdx.x;

    __shared__ uint32 hc[NBINS], hg[NBINS];
    __shared__ uint32 wbc[8], wbg[8], wexc[8], wexg[8];
    __shared__ float wsum[8];

    for (int i = t; i < NBINS; i += 512){
        uint32 c = 0, g = 0;
        for (int sp = 0; sp < S; sp++){
            uint32 v = part[((size_t)(b*S + sp)*NID + k)*NBINS + i];
            c += v >> 16; g += v & 0xFFFFu;
        }
        hc[i] = c; hg[i] = g;
    }
    __syncthreads();

    const int BPT = NBINS/512;       // 2
    int base = t*BPT;
    uint32 c = 0, g = 0;
    #pragma unroll
    for (int i = 0; i < BPT; i++){
        int bin = NBINS-1 - (base+i);
        c += hc[bin]; g += hg[bin];
    }
    uint32 ci = c, gi = g;
    int lane = t & 63, w = t >> 6;
    for (int o = 1; o < 64; o <<= 1){
        uint32 cu = __shfl_up(ci, o);
        uint32 gu = __shfl_up(gi, o);
        if (lane >= o){ ci += cu; gi += gu; }
    }
    if (lane == 63){ wbc[w] = ci; wbg[w] = gi; }
    __syncthreads();
    if (t == 0){
        uint32 rc = 0, rg = 0;
        for (int i = 0; i < 8; i++){
            uint32 a = wbc[i], bq = wbg[i];
            wexc[i] = rc; wexg[i] = rg;
            rc += a; rg += bq;
        }
    }
    __syncthreads();

    float G = stats[b*60 + k*4];
    float contrib = 0.0f;
    if (G > 0.0f){
        uint32 n  = wexc[w] + (ci - c);
        uint32 gg = wexg[w] + (gi - g);
        float jp = 0.0f;
        if (n > 0) jp = 1.0f - (G - (float)gg)/(G + (float)(n - gg));
        #pragma unroll
        for (int i = 0; i < BPT; i++){
            int bin = NBINS-1 - (base+i);
            uint32 cc = hc[bin], cg = hg[bin];
            if (cc | cg){
                n += cc; gg += cg;
                float j2 = 1.0f - (G - (float)gg)/(G + (float)(n - gg));
                float ev = __expf(LN2*(((float)bin + 0.5f)*(13.0f/(float)NBINS) - 12.0f));
                contrib += ev*(j2 - jp);
                jp = j2;
            }
        }
    }
    for (int o = 32; o; o >>= 1) contrib += __shfl_xor(contrib, o);
    if ((t & 63) == 0) wsum[w] = contrib;
    __syncthreads();
    if (t == 0){
        float sres = 0.0f;
        for (int i = 0; i < 8; i++) sres += wsum[i];
        results[(size_t)seg*3 + 0] = sres;
    }
    if (w == 1){
        float v = 0.0f, ss = 0.0f;
        for (int sp = lane; sp < S; sp += 64){
            float2 p2 = part2[(size_t)(b*S + sp)*NID + k];
            v += p2.x; ss += p2.y;
        }
        for (int o = 32; o; o >>= 1){
            v += __shfl_xor(v, o);
            ss += __shfl_xor(ss, o);
        }
        if (lane == 0){
            results[(size_t)seg*3 + 1] = v;
            results[(size_t)seg*3 + 2] = ss;
        }
    }
}

// ---------------- phase5: final combine ----------------
__global__ void phase5(const float* __restrict__ stats, const float* __restrict__ results,
                       const float* __restrict__ bgseedR, const float* __restrict__ focalR,
                       float* __restrict__ out){
    int t = threadIdx.x;
    __shared__ float per_b[BB];
    if (t < BB){
        float nvalid = 0.0f, lsum = 0.0f, vsum = 0.0f, ssum = 0.0f;
        for (int k = 0; k < NID; k++){
            int seg = t*NID + k;
            float cnt = stats[t*60 + k*4];
            if (cnt > 0.0f){
                nvalid += 1.0f;
                lsum += results[seg*3+0];
                vsum += results[seg*3+1]/cnt;
                ssum += results[seg*3+2];
            }
        }
        float nobj = fmaxf(nvalid, 1.0f);
        per_b[t] = lsum/nobj + 10.0f*(vsum/nobj) + (bgseedR[t] + ssum)/(float)HWH;
    }
    __syncthreads();
    if (t == 0){
        float s = 0.0f, fs = 0.0f;
        for (int b = 0; b < BB; b++){ s += per_b[b]; fs += focalR[b]; }
        out[0] = s/(float)BB + fs/(float)(BB*HWH);
    }
}

extern "C" void kernel_launch(void* const* d_in, const int* in_sizes, int n_in,
                              void* d_out, int out_size, void* d_ws, size_t ws_size,
                              hipStream_t stream){
    const float* pred  = (const float*)d_in[0];
    const int*   labels= (const int*)d_in[1];
    const int*   inst  = (const int*)d_in[2];
    float* out = (float*)d_out;

    auto need = [](int S){
        return (size_t)BB*S*NID*NBINS*4ull       // hist slabs (u32)
             + (size_t)BB*S*NID*8ull             // var/seed partials (float2)
             + 2048ull*16*8 + 2048ull*16*4       // pstat64 + pstatf
             + 2048ull*4*2                        // focal_p, bgseed_p
             + (480+480+360+8+8)*4ull;
    };
    int S = 8;
    if      (ws_size >= need(64)) S = 64;
    else if (ws_size >= need(32)) S = 32;
    else if (ws_size >= need(16)) S = 16;

    uint32* part   = (uint32*)d_ws;
    float2* part2  = (float2*)((char*)d_ws + (size_t)BB*S*NID*NBINS*4ull);
    uint64* pstat64= (uint64*)(part2 + (size_t)BB*S*NID);
    float* pstatf  = (float*)(pstat64 + 2048*16);
    float* focal_p = pstatf + 2048*16;
    float* bgseed_p= focal_p + 2048;
    float* stats   = bgseed_p + 2048;
    float* derived = stats + 480;
    float* results = derived + 480;
    float* focalR  = results + 360;
    float* bgseedR = focalR + 8;

    hipLaunchKernelGGL(phase1f, dim3(2048), dim3(256), 0, stream,
                       pred, labels, inst, pstat64, pstatf, bgseed_p, focal_p);
    hipLaunchKernelGGL(phaseR, dim3(8), dim3(512), 0, stream,
                       pstat64, pstatf, focal_p, bgseed_p, stats, derived, focalR, bgseedR);
    hipLaunchKernelGGL(phaseLH, dim3(BB*S*2), dim3(512), 0, stream,
                       pred, inst, derived, part, part2, S);
    hipLaunchKernelGGL(phaseLS, dim3(NSEG), dim3(512), 0, stream,
                       part, part2, stats, results, S);
    hipLaunchKernelGGL(phase5, dim3(1), dim3(64), 0, stream,
                       stats, results, bgseedR, focalR, out);
}